// Round 4
// baseline (226.572 us; speedup 1.0000x reference)
//
#include <hip/hip_runtime.h>
#include <hip/hip_bf16.h>
#include <math.h>

#define BATCHN  16
#define SEQ     1024
#define DMODEL  256
#define DSTATE  128
#define HEADDIM 64
#define DINNER  512
#define NHEADS  8
#define CONVDIM 768
#define DINPROJ 1288
#define ZXLD    1280
#define KCONV   4
#define NCHUNK  16
#define LCHUNK  64
#define EPSV    1e-5f
#define ROWS    (BATCHN*SEQ)

typedef __attribute__((ext_vector_type(8))) __bf16 bf16x8;
typedef __attribute__((ext_vector_type(4))) float  f32x4;

__device__ inline ushort f2bf(float f) {
    union { float f; uint32_t u; } v; v.f = f;
    uint32_t r = v.u + 0x7fff + ((v.u >> 16) & 1);
    return (ushort)(r >> 16);
}
__device__ inline float bf2f(ushort u) {
    union { uint32_t u; float f; } v; v.u = ((uint32_t)u) << 16;
    return v.f;
}
__device__ inline uint4 pack8(float4 a, float4 b) {
    uint4 r;
    r.x = (uint32_t)f2bf(a.x) | ((uint32_t)f2bf(a.y) << 16);
    r.y = (uint32_t)f2bf(a.z) | ((uint32_t)f2bf(a.w) << 16);
    r.z = (uint32_t)f2bf(b.x) | ((uint32_t)f2bf(b.y) << 16);
    r.w = (uint32_t)f2bf(b.z) | ((uint32_t)f2bf(b.w) << 16);
    return r;
}

// ---------------------------------------------- W transpose + cast to bf16
__global__ __launch_bounds__(256) void transpose_cast_k(const float* __restrict__ src,
                                                        ushort* __restrict__ dst,
                                                        int K, int ldsrc, int col0) {
    __shared__ float Ts[32][33];
    const int tx = threadIdx.x & 31, ty = threadIdx.x >> 5;
    const int n0 = blockIdx.x * 32, k0 = blockIdx.y * 32;
    #pragma unroll
    for (int j = 0; j < 4; ++j) {
        int kl = ty * 4 + j;
        Ts[kl][tx] = src[(size_t)(k0 + kl) * ldsrc + col0 + n0 + tx];
    }
    __syncthreads();
    #pragma unroll
    for (int j = 0; j < 4; ++j) {
        int nl = ty * 4 + j;
        dst[(size_t)(n0 + nl) * K + k0 + tx] = f2bf(Ts[tx][nl]);
    }
}

// ------------------------------------------------------- bf16 MFMA GEMM
// A: float (cast) or ushort (bf16 direct). C: float or ushort.
#define LDSW 40
template<typename AT, typename CT>
__global__ __launch_bounds__(256) void gemm_bf16(const AT* __restrict__ A,
                                                 const ushort* __restrict__ Bt,
                                                 CT* __restrict__ C,
                                                 int M, int N, int K) {
    __shared__ ushort As[128 * LDSW];
    __shared__ ushort Bs[128 * LDSW];
    const int tid  = threadIdx.x;
    const int m0 = blockIdx.y * 128, n0 = blockIdx.x * 128;
    const int wid = tid >> 6, lane = tid & 63;
    const int wr = wid >> 1, wc = wid & 1;
    const int r = tid >> 1, kq = tid & 1;
    const int fr = lane & 15, kc = lane >> 4;

    f32x4 acc[4][4];
    #pragma unroll
    for (int i = 0; i < 4; ++i)
        #pragma unroll
        for (int j = 0; j < 4; ++j) acc[i][j] = (f32x4)0.f;

    for (int kt = 0; kt < K; kt += 32) {
        if constexpr (sizeof(AT) == 4) {
            const float* ap = (const float*)&A[(size_t)(m0 + r) * K + kt + kq * 16];
            float4 v0 = *(const float4*)(ap + 0);
            float4 v1 = *(const float4*)(ap + 4);
            float4 v2 = *(const float4*)(ap + 8);
            float4 v3 = *(const float4*)(ap + 12);
            *(uint4*)&As[r * LDSW + kq * 16]     = pack8(v0, v1);
            *(uint4*)&As[r * LDSW + kq * 16 + 8] = pack8(v2, v3);
        } else {
            const ushort* ap = (const ushort*)&A[(size_t)(m0 + r) * K + kt + kq * 16];
            *(uint4*)&As[r * LDSW + kq * 16]     = *(const uint4*)(ap);
            *(uint4*)&As[r * LDSW + kq * 16 + 8] = *(const uint4*)(ap + 8);
        }
        const ushort* bp = &Bt[(size_t)(n0 + r) * K + kt + kq * 16];
        *(uint4*)&Bs[r * LDSW + kq * 16]     = *(const uint4*)(bp);
        *(uint4*)&Bs[r * LDSW + kq * 16 + 8] = *(const uint4*)(bp + 8);
        __syncthreads();
        bf16x8 af[4], bfv[4];
        #pragma unroll
        for (int i = 0; i < 4; ++i) {
            af[i]  = *(const bf16x8*)&As[(wr * 64 + i * 16 + fr) * LDSW + kc * 8];
            bfv[i] = *(const bf16x8*)&Bs[(wc * 64 + i * 16 + fr) * LDSW + kc * 8];
        }
        #pragma unroll
        for (int i = 0; i < 4; ++i)
            #pragma unroll
            for (int j = 0; j < 4; ++j)
                acc[i][j] = __builtin_amdgcn_mfma_f32_16x16x32_bf16(af[i], bfv[j], acc[i][j], 0, 0, 0);
        __syncthreads();
    }
    #pragma unroll
    for (int i = 0; i < 4; ++i)
        #pragma unroll
        for (int j = 0; j < 4; ++j)
            #pragma unroll
            for (int q = 0; q < 4; ++q) {
                int rr = m0 + wr * 64 + i * 16 + (lane >> 4) * 4 + q;
                int cc = n0 + wc * 64 + j * 16 + (lane & 15);
                if constexpr (sizeof(CT) == 4) C[(size_t)rr * N + cc] = acc[i][j][q];
                else                           C[(size_t)rr * N + cc] = f2bf(acc[i][j][q]);
            }
}

// ------------------------------------------------- dt path: exact f32 GEMV
__global__ __launch_bounds__(256) void dt_fused_k(const float* __restrict__ u,
                                                  const float* __restrict__ W_in,
                                                  const float* __restrict__ dt_bias,
                                                  const float* __restrict__ A_log,
                                                  float* __restrict__ dtb,
                                                  float* __restrict__ adtb) {
    __shared__ float Ws[DMODEL][NHEADS];
    const int tid = threadIdx.x;
    #pragma unroll
    for (int j = 0; j < 8; ++j) {
        int idx = tid + j * 256;
        Ws[idx >> 3][idx & 7] = W_in[(size_t)(idx >> 3) * DINPROJ + 1280 + (idx & 7)];
    }
    __syncthreads();
    const int lane = tid & 63, w = tid >> 6;
    const int h = lane & 7;
    const int row = blockIdx.x * 32 + w * 8 + (lane >> 3);
    const float* up = &u[(size_t)row * DMODEL];
    float acc = 0.f;
    for (int k = 0; k < DMODEL; k += 4) {
        float4 uv = *(const float4*)(up + k);
        acc += uv.x * Ws[k][h] + uv.y * Ws[k+1][h] + uv.z * Ws[k+2][h] + uv.w * Ws[k+3][h];
    }
    float v = acc + dt_bias[h];
    float dt = (v > 20.f) ? v : log1pf(__expf(v));
    dtb [(size_t)row * NHEADS + h] = dt;
    adtb[(size_t)row * NHEADS + h] = dt * (-__expf(A_log[h]));
}

// ------------------------------------------------- depthwise conv + SiLU (bf16 in/out)
__global__ __launch_bounds__(256) void conv_silu_k(const ushort* __restrict__ zx,
                                                   const float* __restrict__ cw,
                                                   const float* __restrict__ cb,
                                                   ushort* __restrict__ out) {
    const int idx = blockIdx.x * 256 + threadIdx.x;   // ROWS * 96
    const int cg = idx % 96, bt = idx / 96;
    const int t = bt & (SEQ - 1);
    const int c0 = cg * 8;
    float acc[8];
    #pragma unroll
    for (int j = 0; j < 8; ++j) acc[j] = cb[c0 + j];
    #pragma unroll
    for (int k = 0; k < KCONV; ++k) {
        int tt = t - (KCONV - 1) + k;
        if (tt < 0) continue;
        uint4 v = *(const uint4*)&zx[(size_t)(bt - (KCONV - 1) + k) * ZXLD + DINNER + c0];
        const ushort* pv = (const ushort*)&v;
        #pragma unroll
        for (int j = 0; j < 8; ++j) acc[j] += bf2f(pv[j]) * cw[(c0 + j) * KCONV + k];
    }
    ushort res[8];
    #pragma unroll
    for (int j = 0; j < 8; ++j) {
        float s = acc[j] / (1.f + __expf(-acc[j]));
        res[j] = f2bf(s);
    }
    *(uint4*)&out[(size_t)bt * CONVDIM + c0] = *(uint4*)res;
}

// -------------------------------------------------- SSD MFMA kernel
#define SLDA 136
#define SLDB 72
__global__ __launch_bounds__(256) void ssd_mfma_k(const ushort* __restrict__ xbc,
                                                  const float* __restrict__ dtb,
                                                  const float* __restrict__ adtb,
                                                  const float* __restrict__ Dp,
                                                  ushort* __restrict__ ybuf,
                                                  ushort* __restrict__ states,
                                                  float* __restrict__ acsbuf,
                                                  float* __restrict__ chunksum) {
    const int c = blockIdx.x, b = blockIdx.y, hgrp = blockIdx.z;
    const int row0 = b * SEQ + c * LCHUNK;
    const int tid = threadIdx.x;
    const int lane = tid & 63, w = tid >> 6;
    const int fr = lane & 15, kc = lane >> 4;

    __shared__ union {
        struct { ushort Bs[64][SLDA]; ushort Cs[64][SLDA]; } p1;
        struct { ushort Ps[64][SLDB]; ushort Xt[64][SLDB]; ushort Xdt[64][SLDB]; } p2;
    } U;
    __shared__ ushort Btr[128][SLDB];
    __shared__ float acs4[4][64];
    __shared__ float dts[4][64];

    {
        const int hh = hgrp * 4 + w;
        float v = adtb[(size_t)(row0 + lane) * NHEADS + hh];
        #pragma unroll
        for (int off = 1; off < 64; off <<= 1) {
            float t = __shfl_up(v, off);
            if (lane >= off) v += t;
        }
        acs4[w][lane] = v;
        acsbuf[(((size_t)b * NCHUNK + c) * NHEADS + hh) * LCHUNK + lane] = v;
        if (lane == 63) chunksum[((size_t)b * NCHUNK + c) * NHEADS + hh] = v;
        dts[w][lane] = dtb[(size_t)(row0 + lane) * NHEADS + hh];
    }
    for (int it = 0; it < 4; ++it) {
        int idx = tid + it * 256;
        int l = idx >> 4, ng = idx & 15;
        const ushort* rp = &xbc[(size_t)(row0 + l) * CONVDIM + DINNER];
        uint4 vb = *(const uint4*)(rp + ng * 8);
        *(uint4*)&U.p1.Bs[l][ng * 8] = vb;
        uint4 vc = *(const uint4*)(rp + DSTATE + ng * 8);
        *(uint4*)&U.p1.Cs[l][ng * 8] = vc;
        const ushort* pv = (const ushort*)&vb;
        #pragma unroll
        for (int j = 0; j < 8; ++j) Btr[ng * 8 + j][l] = pv[j];
    }
    __syncthreads();

    const int wr = w >> 1, wc = w & 1;
    f32x4 accG[2][2];
    #pragma unroll
    for (int i = 0; i < 2; ++i)
        #pragma unroll
        for (int j = 0; j < 2; ++j) accG[i][j] = (f32x4)0.f;
    #pragma unroll
    for (int kt = 0; kt < 4; ++kt) {
        bf16x8 af[2], bfv[2];
        #pragma unroll
        for (int i = 0; i < 2; ++i) af[i]  = *(const bf16x8*)&U.p1.Cs[wr*32 + i*16 + fr][kt*32 + kc*8];
        #pragma unroll
        for (int j = 0; j < 2; ++j) bfv[j] = *(const bf16x8*)&U.p1.Bs[wc*32 + j*16 + fr][kt*32 + kc*8];
        #pragma unroll
        for (int i = 0; i < 2; ++i)
            #pragma unroll
            for (int j = 0; j < 2; ++j)
                accG[i][j] = __builtin_amdgcn_mfma_f32_16x16x32_bf16(af[i], bfv[j], accG[i][j], 0, 0, 0);
    }
    __syncthreads();

    for (int hl = 0; hl < 4; ++hl) {
        const int hh = hgrp * 4 + hl;
        const float acsL = acs4[hl][63];
        const float dec_l = __expf(acsL - acs4[hl][lane]);
        const float dt_l  = dts[hl][lane];
        #pragma unroll
        for (int i = 0; i < 4; ++i) {
            int p0 = w * 16 + i * 4;
            ushort4 xv = *(const ushort4*)&xbc[(size_t)(row0 + lane) * CONVDIM + hh * HEADDIM + p0];
            float x0 = bf2f(xv.x) * dt_l, x1 = bf2f(xv.y) * dt_l;
            float x2 = bf2f(xv.z) * dt_l, x3 = bf2f(xv.w) * dt_l;
            U.p2.Xt [p0+0][lane] = f2bf(x0); U.p2.Xdt[p0+0][lane] = f2bf(x0 * dec_l);
            U.p2.Xt [p0+1][lane] = f2bf(x1); U.p2.Xdt[p0+1][lane] = f2bf(x1 * dec_l);
            U.p2.Xt [p0+2][lane] = f2bf(x2); U.p2.Xdt[p0+2][lane] = f2bf(x2 * dec_l);
            U.p2.Xt [p0+3][lane] = f2bf(x3); U.p2.Xdt[p0+3][lane] = f2bf(x3 * dec_l);
        }
        #pragma unroll
        for (int i = 0; i < 2; ++i)
            #pragma unroll
            for (int j = 0; j < 2; ++j)
                #pragma unroll
                for (int q = 0; q < 4; ++q) {
                    int l = wr*32 + i*16 + (lane >> 4)*4 + q;
                    int s = wc*32 + j*16 + fr;
                    float v = 0.f;
                    if (s < l)       v = accG[i][j][q] * __expf(acs4[hl][l] - acs4[hl][s]);
                    else if (s == l) v = accG[i][j][q] + Dp[hh] / dts[hl][l];
                    U.p2.Ps[l][s] = f2bf(v);
                }
        __syncthreads();
        {
            f32x4 acc[4];
            #pragma unroll
            for (int j = 0; j < 4; ++j) acc[j] = (f32x4)0.f;
            #pragma unroll
            for (int kt = 0; kt < 2; ++kt) {
                bf16x8 af = *(const bf16x8*)&U.p2.Ps[w*16 + fr][kt*32 + kc*8];
                #pragma unroll
                for (int j = 0; j < 4; ++j) {
                    bf16x8 bfv = *(const bf16x8*)&U.p2.Xt[j*16 + fr][kt*32 + kc*8];
                    acc[j] = __builtin_amdgcn_mfma_f32_16x16x32_bf16(af, bfv, acc[j], 0, 0, 0);
                }
            }
            #pragma unroll
            for (int j = 0; j < 4; ++j)
                #pragma unroll
                for (int q = 0; q < 4; ++q) {
                    int l = w*16 + (lane >> 4)*4 + q;
                    int p = j*16 + fr;
                    ybuf[(size_t)(row0 + l) * DINNER + hh * HEADDIM + p] = f2bf(acc[j][q]);
                }
        }
        {
            f32x4 acc2[4][2];
            #pragma unroll
            for (int mt = 0; mt < 4; ++mt)
                #pragma unroll
                for (int jt = 0; jt < 2; ++jt) acc2[mt][jt] = (f32x4)0.f;
            #pragma unroll
            for (int kt = 0; kt < 2; ++kt) {
                bf16x8 a4[4], b2[2];
                #pragma unroll
                for (int mt = 0; mt < 4; ++mt) a4[mt] = *(const bf16x8*)&U.p2.Xdt[mt*16 + fr][kt*32 + kc*8];
                #pragma unroll
                for (int jt = 0; jt < 2; ++jt) b2[jt] = *(const bf16x8*)&Btr[w*32 + jt*16 + fr][kt*32 + kc*8];
                #pragma unroll
                for (int mt = 0; mt < 4; ++mt)
                    #pragma unroll
                    for (int jt = 0; jt < 2; ++jt)
                        acc2[mt][jt] = __builtin_amdgcn_mfma_f32_16x16x32_bf16(a4[mt], b2[jt], acc2[mt][jt], 0, 0, 0);
            }
            ushort* sb = states + ((((size_t)b * NCHUNK + c) * NHEADS + hh) * HEADDIM) * DSTATE;
            #pragma unroll
            for (int mt = 0; mt < 4; ++mt)
                #pragma unroll
                for (int jt = 0; jt < 2; ++jt)
                    #pragma unroll
                    for (int q = 0; q < 4; ++q) {
                        int p = mt*16 + (lane >> 4)*4 + q;
                        int n = w*32 + jt*16 + fr;
                        sb[(size_t)p * DSTATE + n] = f2bf(acc2[mt][jt][q]);
                    }
        }
        __syncthreads();
    }
}

// ------------------------------------- inter-chunk scan (bf16 states, f32 regs)
__global__ __launch_bounds__(256) void scan_k(ushort* __restrict__ states,
                                              const float* __restrict__ chunksum) {
    const int bid = blockIdx.x;          // B*H*4 = 512
    const int pq = bid & 3, h = (bid >> 2) & 7, b = bid >> 5;
    const int tid = threadIdx.x;
    float pref[8];
    #pragma unroll
    for (int k = 0; k < 8; ++k) pref[k] = 0.f;
    for (int c = 0; c < NCHUNK; ++c) {
        ushort* base = states + (((size_t)b * NCHUNK + c) * NHEADS + h) * (HEADDIM * DSTATE)
                       + pq * 2048 + tid * 8;
        float dec = __expf(chunksum[((size_t)b * NCHUNK + c) * NHEADS + h]);
        uint4 v = *(const uint4*)base;
        const ushort* pv = (const ushort*)&v;
        ushort outv[8];
        #pragma unroll
        for (int j = 0; j < 8; ++j) {
            float cur = bf2f(pv[j]);
            outv[j] = f2bf(pref[j]);
            pref[j] = dec * pref[j] + cur;
        }
        *(uint4*)base = *(uint4*)outv;
    }
}

// ------------------- Y_off += C @ S^T * ea, then gate+RMSNorm, write bf16 g
#define YLDS 520
__global__ __launch_bounds__(256) void yoff_gate_k(const ushort* __restrict__ xbc,
                                                   const ushort* __restrict__ states,
                                                   const float* __restrict__ acsbuf,
                                                   const ushort* __restrict__ ybuf,
                                                   const ushort* __restrict__ zx,
                                                   const float* __restrict__ nw,
                                                   ushort* __restrict__ gbuf) {
    const int c = blockIdx.x, b = blockIdx.y;
    const int row0 = b * SEQ + c * LCHUNK;
    const int tid = threadIdx.x;
    const int lane = tid & 63, w = tid >> 6;
    const int fr = lane & 15, kc = lane >> 4;
    __shared__ ushort Csh[64][SLDA];
    __shared__ ushort Ssh[64][SLDA];
    __shared__ ushort Ys[64][YLDS];
    __shared__ float eah[64];

    for (int it = 0; it < 4; ++it) {
        int idx = tid + it * 256;
        int l = idx >> 4, ng = idx & 15;
        *(uint4*)&Csh[l][ng * 8] =
            *(const uint4*)&xbc[(size_t)(row0 + l) * CONVDIM + DINNER + DSTATE + ng * 8];
    }
    for (int hl = 0; hl < NHEADS; ++hl) {
        __syncthreads();   // Ssh free (and covers Csh staging on first iter)
        const ushort* sb = states + ((((size_t)b * NCHUNK + c) * NHEADS + hl) * HEADDIM) * DSTATE;
        for (int it = 0; it < 4; ++it) {
            int idx = tid + it * 256;
            int p = idx >> 4, ng = idx & 15;
            *(uint4*)&Ssh[p][ng * 8] = *(const uint4*)&sb[(size_t)p * DSTATE + ng * 8];
        }
        if (tid < 64)
            eah[tid] = __expf(acsbuf[(((size_t)b * NCHUNK + c) * NHEADS + hl) * LCHUNK + tid]);
        __syncthreads();
        f32x4 acc[4];
        #pragma unroll
        for (int j = 0; j < 4; ++j) acc[j] = (f32x4)0.f;
        #pragma unroll
        for (int kt = 0; kt < 4; ++kt) {
            bf16x8 af = *(const bf16x8*)&Csh[w*16 + fr][kt*32 + kc*8];
            #pragma unroll
            for (int j = 0; j < 4; ++j) {
                bf16x8 bfv = *(const bf16x8*)&Ssh[j*16 + fr][kt*32 + kc*8];
                acc[j] = __builtin_amdgcn_mfma_f32_16x16x32_bf16(af, bfv, acc[j], 0, 0, 0);
            }
        }
        #pragma unroll
        for (int j = 0; j < 4; ++j)
            #pragma unroll
            for (int q = 0; q < 4; ++q) {
                int l = w*16 + (lane >> 4)*4 + q;
                int p = j*16 + fr;
                float val = bf2f(ybuf[(size_t)(row0 + l) * DINNER + hl * HEADDIM + p])
                            + acc[j][q] * eah[l];
                Ys[l][hl * HEADDIM + p] = f2bf(val);
            }
    }
    __syncthreads();
    // gate + RMSNorm phase: wave w handles rows w*16 .. w*16+15
    float nwv[8];
    #pragma unroll
    for (int j = 0; j < 8; ++j) nwv[j] = nw[lane * 8 + j];
    for (int i = 0; i < 16; ++i) {
        int l = w * 16 + i;
        int row = row0 + l;
        uint4 zv = *(const uint4*)&zx[(size_t)row * ZXLD + lane * 8];
        const ushort* pz = (const ushort*)&zv;
        float g[8], ss = 0.f;
        #pragma unroll
        for (int j = 0; j < 8; ++j) {
            float y = bf2f(Ys[l][lane * 8 + j]);
            float z = bf2f(pz[j]);
            float sz = z / (1.f + __expf(-z));
            g[j] = y * sz;
            ss += g[j] * g[j];
        }
        #pragma unroll
        for (int off = 32; off; off >>= 1) ss += __shfl_xor(ss, off);
        float r = rsqrtf(ss / (float)DINNER + EPSV);
        ushort res[8];
        #pragma unroll
        for (int j = 0; j < 8; ++j) res[j] = f2bf(g[j] * r * nwv[j]);
        *(uint4*)&gbuf[(size_t)row * DINNER + lane * 8] = *(uint4*)res;
    }
}

// ---------------------------------------------------------------- launch
extern "C" void kernel_launch(void* const* d_in, const int* in_sizes, int n_in,
                              void* d_out, int out_size, void* d_ws, size_t ws_size,
                              hipStream_t stream) {
    const float* u       = (const float*)d_in[0];
    const float* W_in    = (const float*)d_in[1];
    const float* conv_w  = (const float*)d_in[2];
    const float* conv_b  = (const float*)d_in[3];
    const float* dt_bias = (const float*)d_in[4];
    const float* A_log   = (const float*)d_in[5];
    const float* Dp      = (const float*)d_in[6];
    const float* norm_w  = (const float*)d_in[7];
    const float* W_out   = (const float*)d_in[8];
    float* out = (float*)d_out;

    char* p = (char*)d_ws;
    ushort* zx       = (ushort*)p; p += (size_t)ROWS * ZXLD * sizeof(ushort);    // 41.9 MB
    ushort* ybuf     = (ushort*)p; p += (size_t)ROWS * DINNER * sizeof(ushort);  // 16.8 MB
    ushort* gbuf     = (ushort*)p; p += (size_t)ROWS * DINNER * sizeof(ushort);  // 16.8 MB
    ushort* states   = (ushort*)p; p += (size_t)BATCHN * NCHUNK * NHEADS * HEADDIM * DSTATE * sizeof(ushort); // 33.5 MB
    ushort* xbc      = (ushort*)p; p += (size_t)ROWS * CONVDIM * sizeof(ushort); // 25.2 MB
    float*  dtb      = (float*)p;  p += (size_t)ROWS * NHEADS  * sizeof(float);
    float*  adtb     = (float*)p;  p += (size_t)ROWS * NHEADS  * sizeof(float);
    float*  chunksum = (float*)p;  p += (size_t)BATCHN * NCHUNK * NHEADS * sizeof(float);
    float*  acsbuf   = (float*)p;  p += (size_t)BATCHN * NCHUNK * NHEADS * LCHUNK * sizeof(float);
    ushort* WtA      = (ushort*)p; p += (size_t)ZXLD * DMODEL * sizeof(ushort);
    ushort* WtB      = (ushort*)p; p += (size_t)DMODEL * DINNER * sizeof(ushort);

    transpose_cast_k<<<dim3(ZXLD/32, DMODEL/32), 256, 0, stream>>>(W_in,  WtA, DMODEL, DINPROJ, 0);
    transpose_cast_k<<<dim3(DMODEL/32, DINNER/32), 256, 0, stream>>>(W_out, WtB, DINNER, DMODEL, 0);
    // in-proj -> bf16 zx
    gemm_bf16<float, ushort><<<dim3(ZXLD/128, ROWS/128), 256, 0, stream>>>(
        u, WtA, zx, ROWS, ZXLD, DMODEL);
    dt_fused_k<<<ROWS/32, 256, 0, stream>>>(u, W_in, dt_bias, A_log, dtb, adtb);
    conv_silu_k<<<ROWS*96/256, 256, 0, stream>>>(zx, conv_w, conv_b, xbc);
    ssd_mfma_k<<<dim3(NCHUNK, BATCHN, 2), 256, 0, stream>>>(
        xbc, dtb, adtb, Dp, ybuf, states, acsbuf, chunksum);
    scan_k<<<BATCHN*NHEADS*4, 256, 0, stream>>>(states, chunksum);
    yoff_gate_k<<<dim3(NCHUNK, BATCHN), 256, 0, stream>>>(
        xbc, states, acsbuf, ybuf, zx, norm_w, gbuf);
    // out-proj from bf16 g
    gemm_bf16<ushort, float><<<dim3(DMODEL/128, ROWS/128), 256, 0, stream>>>(
        gbuf, WtB, out, ROWS, DMODEL, DINNER);
}

// Round 5
// 148.835 us; speedup vs baseline: 1.5223x; 1.5223x over previous
//
#include <hip/hip_runtime.h>
#include <hip/hip_bf16.h>
#include <math.h>

#define BATCHN  16
#define SEQ     1024
#define DMODEL  256
#define DSTATE  128
#define HEADDIM 64
#define DINNER  512
#define NHEADS  8
#define CONVDIM 768
#define DINPROJ 1288
#define ZXLD    1280
#define KCONV   4
#define NCHUNK  16
#define LCHUNK  64
#define EPSV    1e-5f
#define ROWS    (BATCHN*SEQ)

typedef __attribute__((ext_vector_type(8))) __bf16 bf16x8;
typedef __attribute__((ext_vector_type(4))) float  f32x4;

__device__ inline ushort f2bf(float f) {
    union { float f; uint32_t u; } v; v.f = f;
    uint32_t r = v.u + 0x7fff + ((v.u >> 16) & 1);
    return (ushort)(r >> 16);
}
__device__ inline float bf2f(ushort u) {
    union { uint32_t u; float f; } v; v.u = ((uint32_t)u) << 16;
    return v.f;
}
__device__ inline uint4 pack8(float4 a, float4 b) {
    uint4 r;
    r.x = (uint32_t)f2bf(a.x) | ((uint32_t)f2bf(a.y) << 16);
    r.y = (uint32_t)f2bf(a.z) | ((uint32_t)f2bf(a.w) << 16);
    r.z = (uint32_t)f2bf(b.x) | ((uint32_t)f2bf(b.y) << 16);
    r.w = (uint32_t)f2bf(b.z) | ((uint32_t)f2bf(b.w) << 16);
    return r;
}

// ---------------------------------------------- W transpose + cast to bf16
__global__ __launch_bounds__(256) void transpose_cast_k(const float* __restrict__ src,
                                                        ushort* __restrict__ dst,
                                                        int K, int ldsrc, int col0) {
    __shared__ float Ts[32][33];
    const int tx = threadIdx.x & 31, ty = threadIdx.x >> 5;
    const int n0 = blockIdx.x * 32, k0 = blockIdx.y * 32;
    #pragma unroll
    for (int j = 0; j < 4; ++j) {
        int kl = ty * 4 + j;
        Ts[kl][tx] = src[(size_t)(k0 + kl) * ldsrc + col0 + n0 + tx];
    }
    __syncthreads();
    #pragma unroll
    for (int j = 0; j < 4; ++j) {
        int nl = ty * 4 + j;
        dst[(size_t)(n0 + nl) * K + k0 + tx] = f2bf(Ts[tx][nl]);
    }
}

// ------------------------------------------------------- bf16 MFMA GEMM
#define LDSW 40
template<typename AT, typename CT>
__global__ __launch_bounds__(256) void gemm_bf16(const AT* __restrict__ A,
                                                 const ushort* __restrict__ Bt,
                                                 CT* __restrict__ C,
                                                 int M, int N, int K) {
    __shared__ ushort As[128 * LDSW];
    __shared__ ushort Bs[128 * LDSW];
    const int tid  = threadIdx.x;
    const int m0 = blockIdx.y * 128, n0 = blockIdx.x * 128;
    const int wid = tid >> 6, lane = tid & 63;
    const int wr = wid >> 1, wc = wid & 1;
    const int r = tid >> 1, kq = tid & 1;
    const int fr = lane & 15, kc = lane >> 4;

    f32x4 acc[4][4];
    #pragma unroll
    for (int i = 0; i < 4; ++i)
        #pragma unroll
        for (int j = 0; j < 4; ++j) acc[i][j] = (f32x4)0.f;

    for (int kt = 0; kt < K; kt += 32) {
        if constexpr (sizeof(AT) == 4) {
            const float* ap = (const float*)&A[(size_t)(m0 + r) * K + kt + kq * 16];
            float4 v0 = *(const float4*)(ap + 0);
            float4 v1 = *(const float4*)(ap + 4);
            float4 v2 = *(const float4*)(ap + 8);
            float4 v3 = *(const float4*)(ap + 12);
            *(uint4*)&As[r * LDSW + kq * 16]     = pack8(v0, v1);
            *(uint4*)&As[r * LDSW + kq * 16 + 8] = pack8(v2, v3);
        } else {
            const ushort* ap = (const ushort*)&A[(size_t)(m0 + r) * K + kt + kq * 16];
            *(uint4*)&As[r * LDSW + kq * 16]     = *(const uint4*)(ap);
            *(uint4*)&As[r * LDSW + kq * 16 + 8] = *(const uint4*)(ap + 8);
        }
        const ushort* bp = &Bt[(size_t)(n0 + r) * K + kt + kq * 16];
        *(uint4*)&Bs[r * LDSW + kq * 16]     = *(const uint4*)(bp);
        *(uint4*)&Bs[r * LDSW + kq * 16 + 8] = *(const uint4*)(bp + 8);
        __syncthreads();
        bf16x8 af[4], bfv[4];
        #pragma unroll
        for (int i = 0; i < 4; ++i) {
            af[i]  = *(const bf16x8*)&As[(wr * 64 + i * 16 + fr) * LDSW + kc * 8];
            bfv[i] = *(const bf16x8*)&Bs[(wc * 64 + i * 16 + fr) * LDSW + kc * 8];
        }
        #pragma unroll
        for (int i = 0; i < 4; ++i)
            #pragma unroll
            for (int j = 0; j < 4; ++j)
                acc[i][j] = __builtin_amdgcn_mfma_f32_16x16x32_bf16(af[i], bfv[j], acc[i][j], 0, 0, 0);
        __syncthreads();
    }
    #pragma unroll
    for (int i = 0; i < 4; ++i)
        #pragma unroll
        for (int j = 0; j < 4; ++j)
            #pragma unroll
            for (int q = 0; q < 4; ++q) {
                int rr = m0 + wr * 64 + i * 16 + (lane >> 4) * 4 + q;
                int cc = n0 + wc * 64 + j * 16 + (lane & 15);
                if constexpr (sizeof(CT) == 4) C[(size_t)rr * N + cc] = acc[i][j][q];
                else                           C[(size_t)rr * N + cc] = f2bf(acc[i][j][q]);
            }
}

// ------------------------------------------------- dt path: exact f32 GEMV
__global__ __launch_bounds__(256) void dt_fused_k(const float* __restrict__ u,
                                                  const float* __restrict__ W_in,
                                                  const float* __restrict__ dt_bias,
                                                  const float* __restrict__ A_log,
                                                  float* __restrict__ dtb,
                                                  float* __restrict__ adtb) {
    __shared__ float Ws[DMODEL][NHEADS];
    const int tid = threadIdx.x;
    #pragma unroll
    for (int j = 0; j < 8; ++j) {
        int idx = tid + j * 256;
        Ws[idx >> 3][idx & 7] = W_in[(size_t)(idx >> 3) * DINPROJ + 1280 + (idx & 7)];
    }
    __syncthreads();
    const int lane = tid & 63, w = tid >> 6;
    const int h = lane & 7;
    const int row = blockIdx.x * 32 + w * 8 + (lane >> 3);
    const float* up = &u[(size_t)row * DMODEL];
    float acc = 0.f;
    for (int k = 0; k < DMODEL; k += 4) {
        float4 uv = *(const float4*)(up + k);
        acc += uv.x * Ws[k][h] + uv.y * Ws[k+1][h] + uv.z * Ws[k+2][h] + uv.w * Ws[k+3][h];
    }
    float v = acc + dt_bias[h];
    float dt = (v > 20.f) ? v : log1pf(__expf(v));
    dtb [(size_t)row * NHEADS + h] = dt;
    adtb[(size_t)row * NHEADS + h] = dt * (-__expf(A_log[h]));
}

// ------------------- depthwise conv + SiLU: LDS weights, 4 t-steps/thread
// thread -> (bt0 = 4*btq, channels c0..c0+7). Loads 7 zx rows, writes 4 rows.
__global__ __launch_bounds__(256) void conv_silu_k(const ushort* __restrict__ zx,
                                                   const float* __restrict__ cw,
                                                   const float* __restrict__ cb,
                                                   ushort* __restrict__ out) {
    __shared__ float cws[KCONV][CONVDIM];   // 12 KB, [k][c]
    __shared__ float cbs[CONVDIM];          //  3 KB
    const int tid = threadIdx.x;
    #pragma unroll
    for (int it = 0; it < 3; ++it) {
        int i = tid + it * 256;
        cbs[i] = cb[i];
        #pragma unroll
        for (int k = 0; k < KCONV; ++k) cws[k][i] = cw[i * KCONV + k];
    }
    __syncthreads();

    const int idx = blockIdx.x * 256 + tid;       // ROWS/4 * 96 total
    const int cg = idx % 96, btq = idx / 96;
    const int c0 = cg * 8;
    const int bt0 = btq * 4;
    const int t0 = bt0 & (SEQ - 1);

    float wv[KCONV][8], bias[8];
    #pragma unroll
    for (int j = 0; j < 8; ++j) bias[j] = cbs[c0 + j];
    #pragma unroll
    for (int k = 0; k < KCONV; ++k) {
        float4 a = *(const float4*)&cws[k][c0];
        float4 b = *(const float4*)&cws[k][c0 + 4];
        wv[k][0] = a.x; wv[k][1] = a.y; wv[k][2] = a.z; wv[k][3] = a.w;
        wv[k][4] = b.x; wv[k][5] = b.y; wv[k][6] = b.z; wv[k][7] = b.w;
    }
    // 7 input rows: bt0-3 .. bt0+3
    float xr[7][8];
    #pragma unroll
    for (int r = 0; r < 7; ++r) {
        int tt = t0 - 3 + r;
        if (tt >= 0) {
            uint4 v = *(const uint4*)&zx[(size_t)(bt0 - 3 + r) * ZXLD + DINNER + c0];
            const ushort* pv = (const ushort*)&v;
            #pragma unroll
            for (int j = 0; j < 8; ++j) xr[r][j] = bf2f(pv[j]);
        } else {
            #pragma unroll
            for (int j = 0; j < 8; ++j) xr[r][j] = 0.f;
        }
    }
    #pragma unroll
    for (int dt = 0; dt < 4; ++dt) {
        float acc[8];
        #pragma unroll
        for (int j = 0; j < 8; ++j) acc[j] = bias[j];
        #pragma unroll
        for (int k = 0; k < KCONV; ++k)
            #pragma unroll
            for (int j = 0; j < 8; ++j) acc[j] += xr[dt + k][j] * wv[k][j];
        ushort res[8];
        #pragma unroll
        for (int j = 0; j < 8; ++j)
            res[j] = f2bf(acc[j] / (1.f + __expf(-acc[j])));
        *(uint4*)&out[(size_t)(bt0 + dt) * CONVDIM + c0] = *(uint4*)res;
    }
}

// -------------------------------------------------- SSD MFMA kernel
#define SLDA 136
#define SLDB 72
__global__ __launch_bounds__(256) void ssd_mfma_k(const ushort* __restrict__ xbc,
                                                  const float* __restrict__ dtb,
                                                  const float* __restrict__ adtb,
                                                  const float* __restrict__ Dp,
                                                  ushort* __restrict__ ybuf,
                                                  ushort* __restrict__ states,
                                                  float* __restrict__ acsbuf,
                                                  float* __restrict__ chunksum) {
    const int c = blockIdx.x, b = blockIdx.y, hgrp = blockIdx.z;
    const int row0 = b * SEQ + c * LCHUNK;
    const int tid = threadIdx.x;
    const int lane = tid & 63, w = tid >> 6;
    const int fr = lane & 15, kc = lane >> 4;

    __shared__ union {
        struct { ushort Bs[64][SLDA]; ushort Cs[64][SLDA]; } p1;
        struct { ushort Ps[64][SLDB]; ushort Xt[64][SLDB]; ushort Xdt[64][SLDB]; } p2;
    } U;
    __shared__ ushort Btr[128][SLDB];
    __shared__ float acs4[4][64];
    __shared__ float dts[4][64];

    {
        const int hh = hgrp * 4 + w;
        float v = adtb[(size_t)(row0 + lane) * NHEADS + hh];
        #pragma unroll
        for (int off = 1; off < 64; off <<= 1) {
            float t = __shfl_up(v, off);
            if (lane >= off) v += t;
        }
        acs4[w][lane] = v;
        acsbuf[(((size_t)b * NCHUNK + c) * NHEADS + hh) * LCHUNK + lane] = v;
        if (lane == 63) chunksum[((size_t)b * NCHUNK + c) * NHEADS + hh] = v;
        dts[w][lane] = dtb[(size_t)(row0 + lane) * NHEADS + hh];
    }
    for (int it = 0; it < 4; ++it) {
        int idx = tid + it * 256;
        int l = idx >> 4, ng = idx & 15;
        const ushort* rp = &xbc[(size_t)(row0 + l) * CONVDIM + DINNER];
        uint4 vb = *(const uint4*)(rp + ng * 8);
        *(uint4*)&U.p1.Bs[l][ng * 8] = vb;
        uint4 vc = *(const uint4*)(rp + DSTATE + ng * 8);
        *(uint4*)&U.p1.Cs[l][ng * 8] = vc;
        const ushort* pv = (const ushort*)&vb;
        #pragma unroll
        for (int j = 0; j < 8; ++j) Btr[ng * 8 + j][l] = pv[j];
    }
    __syncthreads();

    const int wr = w >> 1, wc = w & 1;
    f32x4 accG[2][2];
    #pragma unroll
    for (int i = 0; i < 2; ++i)
        #pragma unroll
        for (int j = 0; j < 2; ++j) accG[i][j] = (f32x4)0.f;
    #pragma unroll
    for (int kt = 0; kt < 4; ++kt) {
        bf16x8 af[2], bfv[2];
        #pragma unroll
        for (int i = 0; i < 2; ++i) af[i]  = *(const bf16x8*)&U.p1.Cs[wr*32 + i*16 + fr][kt*32 + kc*8];
        #pragma unroll
        for (int j = 0; j < 2; ++j) bfv[j] = *(const bf16x8*)&U.p1.Bs[wc*32 + j*16 + fr][kt*32 + kc*8];
        #pragma unroll
        for (int i = 0; i < 2; ++i)
            #pragma unroll
            for (int j = 0; j < 2; ++j)
                accG[i][j] = __builtin_amdgcn_mfma_f32_16x16x32_bf16(af[i], bfv[j], accG[i][j], 0, 0, 0);
    }
    __syncthreads();

    for (int hl = 0; hl < 4; ++hl) {
        const int hh = hgrp * 4 + hl;
        const float acsL = acs4[hl][63];
        const float dec_l = __expf(acsL - acs4[hl][lane]);
        const float dt_l  = dts[hl][lane];
        #pragma unroll
        for (int i = 0; i < 4; ++i) {
            int p0 = w * 16 + i * 4;
            ushort4 xv = *(const ushort4*)&xbc[(size_t)(row0 + lane) * CONVDIM + hh * HEADDIM + p0];
            float x0 = bf2f(xv.x) * dt_l, x1 = bf2f(xv.y) * dt_l;
            float x2 = bf2f(xv.z) * dt_l, x3 = bf2f(xv.w) * dt_l;
            U.p2.Xt [p0+0][lane] = f2bf(x0); U.p2.Xdt[p0+0][lane] = f2bf(x0 * dec_l);
            U.p2.Xt [p0+1][lane] = f2bf(x1); U.p2.Xdt[p0+1][lane] = f2bf(x1 * dec_l);
            U.p2.Xt [p0+2][lane] = f2bf(x2); U.p2.Xdt[p0+2][lane] = f2bf(x2 * dec_l);
            U.p2.Xt [p0+3][lane] = f2bf(x3); U.p2.Xdt[p0+3][lane] = f2bf(x3 * dec_l);
        }
        #pragma unroll
        for (int i = 0; i < 2; ++i)
            #pragma unroll
            for (int j = 0; j < 2; ++j)
                #pragma unroll
                for (int q = 0; q < 4; ++q) {
                    int l = wr*32 + i*16 + (lane >> 4)*4 + q;
                    int s = wc*32 + j*16 + fr;
                    float v = 0.f;
                    if (s < l)       v = accG[i][j][q] * __expf(acs4[hl][l] - acs4[hl][s]);
                    else if (s == l) v = accG[i][j][q] + Dp[hh] / dts[hl][l];
                    U.p2.Ps[l][s] = f2bf(v);
                }
        __syncthreads();
        {
            f32x4 acc[4];
            #pragma unroll
            for (int j = 0; j < 4; ++j) acc[j] = (f32x4)0.f;
            #pragma unroll
            for (int kt = 0; kt < 2; ++kt) {
                bf16x8 af = *(const bf16x8*)&U.p2.Ps[w*16 + fr][kt*32 + kc*8];
                #pragma unroll
                for (int j = 0; j < 4; ++j) {
                    bf16x8 bfv = *(const bf16x8*)&U.p2.Xt[j*16 + fr][kt*32 + kc*8];
                    acc[j] = __builtin_amdgcn_mfma_f32_16x16x32_bf16(af, bfv, acc[j], 0, 0, 0);
                }
            }
            #pragma unroll
            for (int j = 0; j < 4; ++j)
                #pragma unroll
                for (int q = 0; q < 4; ++q) {
                    int l = w*16 + (lane >> 4)*4 + q;
                    int p = j*16 + fr;
                    ybuf[(size_t)(row0 + l) * DINNER + hh * HEADDIM + p] = f2bf(acc[j][q]);
                }
        }
        {
            f32x4 acc2[4][2];
            #pragma unroll
            for (int mt = 0; mt < 4; ++mt)
                #pragma unroll
                for (int jt = 0; jt < 2; ++jt) acc2[mt][jt] = (f32x4)0.f;
            #pragma unroll
            for (int kt = 0; kt < 2; ++kt) {
                bf16x8 a4[4], b2[2];
                #pragma unroll
                for (int mt = 0; mt < 4; ++mt) a4[mt] = *(const bf16x8*)&U.p2.Xdt[mt*16 + fr][kt*32 + kc*8];
                #pragma unroll
                for (int jt = 0; jt < 2; ++jt) b2[jt] = *(const bf16x8*)&Btr[w*32 + jt*16 + fr][kt*32 + kc*8];
                #pragma unroll
                for (int mt = 0; mt < 4; ++mt)
                    #pragma unroll
                    for (int jt = 0; jt < 2; ++jt)
                        acc2[mt][jt] = __builtin_amdgcn_mfma_f32_16x16x32_bf16(a4[mt], b2[jt], acc2[mt][jt], 0, 0, 0);
            }
            ushort* sb = states + ((((size_t)b * NCHUNK + c) * NHEADS + hh) * HEADDIM) * DSTATE;
            #pragma unroll
            for (int mt = 0; mt < 4; ++mt)
                #pragma unroll
                for (int jt = 0; jt < 2; ++jt)
                    #pragma unroll
                    for (int q = 0; q < 4; ++q) {
                        int p = mt*16 + (lane >> 4)*4 + q;
                        int n = w*32 + jt*16 + fr;
                        sb[(size_t)p * DSTATE + n] = f2bf(acc2[mt][jt][q]);
                    }
        }
        __syncthreads();
    }
}

// ------------------------------------- inter-chunk scan (bf16 states, f32 regs)
__global__ __launch_bounds__(256) void scan_k(ushort* __restrict__ states,
                                              const float* __restrict__ chunksum) {
    const int bid = blockIdx.x;          // B*H*4 = 512
    const int pq = bid & 3, h = (bid >> 2) & 7, b = bid >> 5;
    const int tid = threadIdx.x;
    float pref[8];
    #pragma unroll
    for (int k = 0; k < 8; ++k) pref[k] = 0.f;
    for (int c = 0; c < NCHUNK; ++c) {
        ushort* base = states + (((size_t)b * NCHUNK + c) * NHEADS + h) * (HEADDIM * DSTATE)
                       + pq * 2048 + tid * 8;
        float dec = __expf(chunksum[((size_t)b * NCHUNK + c) * NHEADS + h]);
        uint4 v = *(const uint4*)base;
        const ushort* pv = (const ushort*)&v;
        ushort outv[8];
        #pragma unroll
        for (int j = 0; j < 8; ++j) {
            float cur = bf2f(pv[j]);
            outv[j] = f2bf(pref[j]);
            pref[j] = dec * pref[j] + cur;
        }
        *(uint4*)base = *(uint4*)outv;
    }
}

// ------------------- Y_off += C @ S^T * ea, then gate+RMSNorm, write bf16 g
#define YLDS 520
__global__ __launch_bounds__(256) void yoff_gate_k(const ushort* __restrict__ xbc,
                                                   const ushort* __restrict__ states,
                                                   const float* __restrict__ acsbuf,
                                                   const ushort* __restrict__ ybuf,
                                                   const ushort* __restrict__ zx,
                                                   const float* __restrict__ nw,
                                                   ushort* __restrict__ gbuf) {
    const int c = blockIdx.x, b = blockIdx.y;
    const int row0 = b * SEQ + c * LCHUNK;
    const int tid = threadIdx.x;
    const int lane = tid & 63, w = tid >> 6;
    const int fr = lane & 15, kc = lane >> 4;
    __shared__ ushort Csh[64][SLDA];
    __shared__ ushort Ssh[64][SLDA];
    __shared__ ushort Ys[64][YLDS];
    __shared__ float eah[64];

    for (int it = 0; it < 4; ++it) {
        int idx = tid + it * 256;
        int l = idx >> 4, ng = idx & 15;
        *(uint4*)&Csh[l][ng * 8] =
            *(const uint4*)&xbc[(size_t)(row0 + l) * CONVDIM + DINNER + DSTATE + ng * 8];
    }
    for (int hl = 0; hl < NHEADS; ++hl) {
        __syncthreads();
        const ushort* sb = states + ((((size_t)b * NCHUNK + c) * NHEADS + hl) * HEADDIM) * DSTATE;
        for (int it = 0; it < 4; ++it) {
            int idx = tid + it * 256;
            int p = idx >> 4, ng = idx & 15;
            *(uint4*)&Ssh[p][ng * 8] = *(const uint4*)&sb[(size_t)p * DSTATE + ng * 8];
        }
        if (tid < 64)
            eah[tid] = __expf(acsbuf[(((size_t)b * NCHUNK + c) * NHEADS + hl) * LCHUNK + tid]);
        __syncthreads();
        f32x4 acc[4];
        #pragma unroll
        for (int j = 0; j < 4; ++j) acc[j] = (f32x4)0.f;
        #pragma unroll
        for (int kt = 0; kt < 4; ++kt) {
            bf16x8 af = *(const bf16x8*)&Csh[w*16 + fr][kt*32 + kc*8];
            #pragma unroll
            for (int j = 0; j < 4; ++j) {
                bf16x8 bfv = *(const bf16x8*)&Ssh[j*16 + fr][kt*32 + kc*8];
                acc[j] = __builtin_amdgcn_mfma_f32_16x16x32_bf16(af, bfv, acc[j], 0, 0, 0);
            }
        }
        #pragma unroll
        for (int j = 0; j < 4; ++j)
            #pragma unroll
            for (int q = 0; q < 4; ++q) {
                int l = w*16 + (lane >> 4)*4 + q;
                int p = j*16 + fr;
                float val = bf2f(ybuf[(size_t)(row0 + l) * DINNER + hl * HEADDIM + p])
                            + acc[j][q] * eah[l];
                Ys[l][hl * HEADDIM + p] = f2bf(val);
            }
    }
    __syncthreads();
    float nwv[8];
    #pragma unroll
    for (int j = 0; j < 8; ++j) nwv[j] = nw[lane * 8 + j];
    for (int i = 0; i < 16; ++i) {
        int l = w * 16 + i;
        int row = row0 + l;
        uint4 zv = *(const uint4*)&zx[(size_t)row * ZXLD + lane * 8];
        const ushort* pz = (const ushort*)&zv;
        float g[8], ss = 0.f;
        #pragma unroll
        for (int j = 0; j < 8; ++j) {
            float y = bf2f(Ys[l][lane * 8 + j]);
            float z = bf2f(pz[j]);
            float sz = z / (1.f + __expf(-z));
            g[j] = y * sz;
            ss += g[j] * g[j];
        }
        #pragma unroll
        for (int off = 32; off; off >>= 1) ss += __shfl_xor(ss, off);
        float r = rsqrtf(ss / (float)DINNER + EPSV);
        ushort res[8];
        #pragma unroll
        for (int j = 0; j < 8; ++j) res[j] = f2bf(g[j] * r * nwv[j]);
        *(uint4*)&gbuf[(size_t)row * DINNER + lane * 8] = *(uint4*)res;
    }
}

// ---------------------------------------------------------------- launch
extern "C" void kernel_launch(void* const* d_in, const int* in_sizes, int n_in,
                              void* d_out, int out_size, void* d_ws, size_t ws_size,
                              hipStream_t stream) {
    const float* u       = (const float*)d_in[0];
    const float* W_in    = (const float*)d_in[1];
    const float* conv_w  = (const float*)d_in[2];
    const float* conv_b  = (const float*)d_in[3];
    const float* dt_bias = (const float*)d_in[4];
    const float* A_log   = (const float*)d_in[5];
    const float* Dp      = (const float*)d_in[6];
    const float* norm_w  = (const float*)d_in[7];
    const float* W_out   = (const float*)d_in[8];
    float* out = (float*)d_out;

    char* p = (char*)d_ws;
    ushort* zx       = (ushort*)p; p += (size_t)ROWS * ZXLD * sizeof(ushort);
    ushort* ybuf     = (ushort*)p; p += (size_t)ROWS * DINNER * sizeof(ushort);
    ushort* gbuf     = (ushort*)p; p += (size_t)ROWS * DINNER * sizeof(ushort);
    ushort* states   = (ushort*)p; p += (size_t)BATCHN * NCHUNK * NHEADS * HEADDIM * DSTATE * sizeof(ushort);
    ushort* xbc      = (ushort*)p; p += (size_t)ROWS * CONVDIM * sizeof(ushort);
    float*  dtb      = (float*)p;  p += (size_t)ROWS * NHEADS  * sizeof(float);
    float*  adtb     = (float*)p;  p += (size_t)ROWS * NHEADS  * sizeof(float);
    float*  chunksum = (float*)p;  p += (size_t)BATCHN * NCHUNK * NHEADS * sizeof(float);
    float*  acsbuf   = (float*)p;  p += (size_t)BATCHN * NCHUNK * NHEADS * LCHUNK * sizeof(float);
    ushort* WtA      = (ushort*)p; p += (size_t)ZXLD * DMODEL * sizeof(ushort);
    ushort* WtB      = (ushort*)p; p += (size_t)DMODEL * DINNER * sizeof(ushort);

    transpose_cast_k<<<dim3(ZXLD/32, DMODEL/32), 256, 0, stream>>>(W_in,  WtA, DMODEL, DINPROJ, 0);
    transpose_cast_k<<<dim3(DMODEL/32, DINNER/32), 256, 0, stream>>>(W_out, WtB, DINNER, DMODEL, 0);
    gemm_bf16<float, ushort><<<dim3(ZXLD/128, ROWS/128), 256, 0, stream>>>(
        u, WtA, zx, ROWS, ZXLD, DMODEL);
    dt_fused_k<<<ROWS/32, 256, 0, stream>>>(u, W_in, dt_bias, A_log, dtb, adtb);
    conv_silu_k<<<(ROWS/4)*96/256, 256, 0, stream>>>(zx, conv_w, conv_b, xbc);
    ssd_mfma_k<<<dim3(NCHUNK, BATCHN, 2), 256, 0, stream>>>(
        xbc, dtb, adtb, Dp, ybuf, states, acsbuf, chunksum);
    scan_k<<<BATCHN*NHEADS*4, 256, 0, stream>>>(states, chunksum);
    yoff_gate_k<<<dim3(NCHUNK, BATCHN), 256, 0, stream>>>(
        xbc, states, acsbuf, ybuf, zx, norm_w, gbuf);
    gemm_bf16<ushort, float><<<dim3(DMODEL/128, ROWS/128), 256, 0, stream>>>(
        gbuf, WtB, out, ROWS, DMODEL, DINNER);
}

// Round 6
// 139.587 us; speedup vs baseline: 1.6232x; 1.0662x over previous
//
#include <hip/hip_runtime.h>
#include <hip/hip_bf16.h>
#include <math.h>

#define BATCHN  16
#define SEQ     1024
#define DMODEL  256
#define DSTATE  128
#define HEADDIM 64
#define DINNER  512
#define NHEADS  8
#define CONVDIM 768
#define DINPROJ 1288
#define ZXLD    1280
#define KCONV   4
#define NCHUNK  16
#define LCHUNK  64
#define EPSV    1e-5f
#define ROWS    (BATCHN*SEQ)

typedef __attribute__((ext_vector_type(8))) __bf16 bf16x8;
typedef __attribute__((ext_vector_type(4))) float  f32x4;

__device__ inline ushort f2bf(float f) {
    union { float f; uint32_t u; } v; v.f = f;
    uint32_t r = v.u + 0x7fff + ((v.u >> 16) & 1);
    return (ushort)(r >> 16);
}
__device__ inline float bf2f(ushort u) {
    union { uint32_t u; float f; } v; v.u = ((uint32_t)u) << 16;
    return v.f;
}

// ---------------------------------------------- f32 -> bf16 cast (vector)
__global__ __launch_bounds__(256) void cast_bf16_k(const float* __restrict__ src,
                                                   ushort* __restrict__ dst) {
    const int idx = blockIdx.x * 256 + threadIdx.x;   // each thread: 8 elems
    float4 a = *(const float4*)&src[(size_t)idx * 8];
    float4 b = *(const float4*)&src[(size_t)idx * 8 + 4];
    ushort r[8];
    r[0]=f2bf(a.x); r[1]=f2bf(a.y); r[2]=f2bf(a.z); r[3]=f2bf(a.w);
    r[4]=f2bf(b.x); r[5]=f2bf(b.y); r[6]=f2bf(b.z); r[7]=f2bf(b.w);
    *(uint4*)&dst[(size_t)idx * 8] = *(uint4*)r;
}

// ---------------------------------------------- W transpose + cast to bf16
__global__ __launch_bounds__(256) void transpose_cast_k(const float* __restrict__ src,
                                                        ushort* __restrict__ dst,
                                                        int K, int ldsrc, int col0) {
    __shared__ float Ts[32][33];
    const int tx = threadIdx.x & 31, ty = threadIdx.x >> 5;
    const int n0 = blockIdx.x * 32, k0 = blockIdx.y * 32;
    #pragma unroll
    for (int j = 0; j < 4; ++j) {
        int kl = ty * 4 + j;
        Ts[kl][tx] = src[(size_t)(k0 + kl) * ldsrc + col0 + n0 + tx];
    }
    __syncthreads();
    #pragma unroll
    for (int j = 0; j < 4; ++j) {
        int nl = ty * 4 + j;
        dst[(size_t)(n0 + nl) * K + k0 + tx] = f2bf(Ts[tx][nl]);
    }
}

// ------------------------------------------------------- bf16 MFMA GEMM
// A[M,K] bf16, Bt[N,K] bf16. BK=64, 128x128 tile, XCD-swizzled 1-D grid.
#define LDSW 72   // 144B row stride
template<typename CT>
__global__ __launch_bounds__(256) void gemm_bf16(const ushort* __restrict__ A,
                                                 const ushort* __restrict__ Bt,
                                                 CT* __restrict__ C,
                                                 int M, int N, int K, int nx) {
    __shared__ ushort As[128 * LDSW];
    __shared__ ushort Bs[128 * LDSW];
    const int tid  = threadIdx.x;
    const int nwg  = gridDim.x;
    const int work = (blockIdx.x & 7) * (nwg >> 3) + (blockIdx.x >> 3);  // XCD-chunked
    const int m0 = (work / nx) * 128, n0 = (work % nx) * 128;
    const int wid = tid >> 6, lane = tid & 63;
    const int wr = wid >> 1, wc = wid & 1;
    const int r = tid >> 1, kq = tid & 1;          // staging: row, 32-elem half
    const int fr = lane & 15, kc = lane >> 4;

    f32x4 acc[4][4];
    #pragma unroll
    for (int i = 0; i < 4; ++i)
        #pragma unroll
        for (int j = 0; j < 4; ++j) acc[i][j] = (f32x4)0.f;

    for (int kt = 0; kt < K; kt += 64) {
        const ushort* ap = &A [(size_t)(m0 + r) * K + kt + kq * 32];
        const ushort* bp = &Bt[(size_t)(n0 + r) * K + kt + kq * 32];
        #pragma unroll
        for (int v = 0; v < 4; ++v) {
            *(uint4*)&As[r * LDSW + kq * 32 + v * 8] = *(const uint4*)(ap + v * 8);
            *(uint4*)&Bs[r * LDSW + kq * 32 + v * 8] = *(const uint4*)(bp + v * 8);
        }
        __syncthreads();
        #pragma unroll
        for (int kk = 0; kk < 2; ++kk) {
            bf16x8 af[4], bfv[4];
            #pragma unroll
            for (int i = 0; i < 4; ++i) {
                af[i]  = *(const bf16x8*)&As[(wr * 64 + i * 16 + fr) * LDSW + kk * 32 + kc * 8];
                bfv[i] = *(const bf16x8*)&Bs[(wc * 64 + i * 16 + fr) * LDSW + kk * 32 + kc * 8];
            }
            #pragma unroll
            for (int i = 0; i < 4; ++i)
                #pragma unroll
                for (int j = 0; j < 4; ++j)
                    acc[i][j] = __builtin_amdgcn_mfma_f32_16x16x32_bf16(af[i], bfv[j], acc[i][j], 0, 0, 0);
        }
        __syncthreads();
    }
    #pragma unroll
    for (int i = 0; i < 4; ++i)
        #pragma unroll
        for (int j = 0; j < 4; ++j)
            #pragma unroll
            for (int q = 0; q < 4; ++q) {
                int rr = m0 + wr * 64 + i * 16 + (lane >> 4) * 4 + q;
                int cc = n0 + wc * 64 + j * 16 + (lane & 15);
                if constexpr (sizeof(CT) == 4) C[(size_t)rr * N + cc] = acc[i][j][q];
                else                           C[(size_t)rr * N + cc] = f2bf(acc[i][j][q]);
            }
}

// ------------------------------------------------- dt path: exact f32 GEMV
__global__ __launch_bounds__(256) void dt_fused_k(const float* __restrict__ u,
                                                  const float* __restrict__ W_in,
                                                  const float* __restrict__ dt_bias,
                                                  const float* __restrict__ A_log,
                                                  float* __restrict__ dtb,
                                                  float* __restrict__ adtb) {
    __shared__ float Ws[DMODEL][NHEADS];
    const int tid = threadIdx.x;
    #pragma unroll
    for (int j = 0; j < 8; ++j) {
        int idx = tid + j * 256;
        Ws[idx >> 3][idx & 7] = W_in[(size_t)(idx >> 3) * DINPROJ + 1280 + (idx & 7)];
    }
    __syncthreads();
    const int lane = tid & 63, w = tid >> 6;
    const int h = lane & 7;
    const int row = blockIdx.x * 32 + w * 8 + (lane >> 3);
    const float* up = &u[(size_t)row * DMODEL];
    float acc = 0.f;
    for (int k = 0; k < DMODEL; k += 4) {
        float4 uv = *(const float4*)(up + k);
        acc += uv.x * Ws[k][h] + uv.y * Ws[k+1][h] + uv.z * Ws[k+2][h] + uv.w * Ws[k+3][h];
    }
    float v = acc + dt_bias[h];
    float dt = (v > 20.f) ? v : log1pf(__expf(v));
    dtb [(size_t)row * NHEADS + h] = dt;
    adtb[(size_t)row * NHEADS + h] = dt * (-__expf(A_log[h]));
}

// ------------------- depthwise conv + SiLU: LDS weights, 4 t-steps/thread
__global__ __launch_bounds__(256) void conv_silu_k(const ushort* __restrict__ zx,
                                                   const float* __restrict__ cw,
                                                   const float* __restrict__ cb,
                                                   ushort* __restrict__ out) {
    __shared__ float cws[KCONV][CONVDIM];
    __shared__ float cbs[CONVDIM];
    const int tid = threadIdx.x;
    #pragma unroll
    for (int it = 0; it < 3; ++it) {
        int i = tid + it * 256;
        cbs[i] = cb[i];
        #pragma unroll
        for (int k = 0; k < KCONV; ++k) cws[k][i] = cw[i * KCONV + k];
    }
    __syncthreads();

    const int idx = blockIdx.x * 256 + tid;
    const int cg = idx % 96, btq = idx / 96;
    const int c0 = cg * 8;
    const int bt0 = btq * 4;
    const int t0 = bt0 & (SEQ - 1);

    float wv[KCONV][8], bias[8];
    #pragma unroll
    for (int j = 0; j < 8; ++j) bias[j] = cbs[c0 + j];
    #pragma unroll
    for (int k = 0; k < KCONV; ++k) {
        float4 a = *(const float4*)&cws[k][c0];
        float4 b = *(const float4*)&cws[k][c0 + 4];
        wv[k][0] = a.x; wv[k][1] = a.y; wv[k][2] = a.z; wv[k][3] = a.w;
        wv[k][4] = b.x; wv[k][5] = b.y; wv[k][6] = b.z; wv[k][7] = b.w;
    }
    float xr[7][8];
    #pragma unroll
    for (int r = 0; r < 7; ++r) {
        int tt = t0 - 3 + r;
        if (tt >= 0) {
            uint4 v = *(const uint4*)&zx[(size_t)(bt0 - 3 + r) * ZXLD + DINNER + c0];
            const ushort* pv = (const ushort*)&v;
            #pragma unroll
            for (int j = 0; j < 8; ++j) xr[r][j] = bf2f(pv[j]);
        } else {
            #pragma unroll
            for (int j = 0; j < 8; ++j) xr[r][j] = 0.f;
        }
    }
    #pragma unroll
    for (int dt = 0; dt < 4; ++dt) {
        float acc[8];
        #pragma unroll
        for (int j = 0; j < 8; ++j) acc[j] = bias[j];
        #pragma unroll
        for (int k = 0; k < KCONV; ++k)
            #pragma unroll
            for (int j = 0; j < 8; ++j) acc[j] += xr[dt + k][j] * wv[k][j];
        ushort res[8];
        #pragma unroll
        for (int j = 0; j < 8; ++j)
            res[j] = f2bf(acc[j] / (1.f + __expf(-acc[j])));
        *(uint4*)&out[(size_t)(bt0 + dt) * CONVDIM + c0] = *(uint4*)res;
    }
}

// -------------------------------------------------- SSD MFMA kernel
#define SLDA 136
#define SLDB 72
__global__ __launch_bounds__(256) void ssd_mfma_k(const ushort* __restrict__ xbc,
                                                  const float* __restrict__ dtb,
                                                  const float* __restrict__ adtb,
                                                  const float* __restrict__ Dp,
                                                  ushort* __restrict__ ybuf,
                                                  ushort* __restrict__ states,
                                                  float* __restrict__ acsbuf,
                                                  float* __restrict__ chunksum) {
    const int c = blockIdx.x, b = blockIdx.y, hgrp = blockIdx.z;
    const int row0 = b * SEQ + c * LCHUNK;
    const int tid = threadIdx.x;
    const int lane = tid & 63, w = tid >> 6;
    const int fr = lane & 15, kc = lane >> 4;

    __shared__ union {
        struct { ushort Bs[64][SLDA]; ushort Cs[64][SLDA]; } p1;
        struct { ushort Ps[64][SLDB]; ushort Xt[64][SLDB]; ushort Xdt[64][SLDB]; } p2;
    } U;
    __shared__ ushort Btr[128][SLDB];
    __shared__ float acs4[4][64];
    __shared__ float dts[4][64];

    {
        const int hh = hgrp * 4 + w;
        float v = adtb[(size_t)(row0 + lane) * NHEADS + hh];
        #pragma unroll
        for (int off = 1; off < 64; off <<= 1) {
            float t = __shfl_up(v, off);
            if (lane >= off) v += t;
        }
        acs4[w][lane] = v;
        acsbuf[(((size_t)b * NCHUNK + c) * NHEADS + hh) * LCHUNK + lane] = v;
        if (lane == 63) chunksum[((size_t)b * NCHUNK + c) * NHEADS + hh] = v;
        dts[w][lane] = dtb[(size_t)(row0 + lane) * NHEADS + hh];
    }
    for (int it = 0; it < 4; ++it) {
        int idx = tid + it * 256;
        int l = idx >> 4, ng = idx & 15;
        const ushort* rp = &xbc[(size_t)(row0 + l) * CONVDIM + DINNER];
        uint4 vb = *(const uint4*)(rp + ng * 8);
        *(uint4*)&U.p1.Bs[l][ng * 8] = vb;
        uint4 vc = *(const uint4*)(rp + DSTATE + ng * 8);
        *(uint4*)&U.p1.Cs[l][ng * 8] = vc;
        const ushort* pv = (const ushort*)&vb;
        #pragma unroll
        for (int j = 0; j < 8; ++j) Btr[ng * 8 + j][l] = pv[j];
    }
    __syncthreads();

    const int wr = w >> 1, wc = w & 1;
    f32x4 accG[2][2];
    #pragma unroll
    for (int i = 0; i < 2; ++i)
        #pragma unroll
        for (int j = 0; j < 2; ++j) accG[i][j] = (f32x4)0.f;
    #pragma unroll
    for (int kt = 0; kt < 4; ++kt) {
        bf16x8 af[2], bfv[2];
        #pragma unroll
        for (int i = 0; i < 2; ++i) af[i]  = *(const bf16x8*)&U.p1.Cs[wr*32 + i*16 + fr][kt*32 + kc*8];
        #pragma unroll
        for (int j = 0; j < 2; ++j) bfv[j] = *(const bf16x8*)&U.p1.Bs[wc*32 + j*16 + fr][kt*32 + kc*8];
        #pragma unroll
        for (int i = 0; i < 2; ++i)
            #pragma unroll
            for (int j = 0; j < 2; ++j)
                accG[i][j] = __builtin_amdgcn_mfma_f32_16x16x32_bf16(af[i], bfv[j], accG[i][j], 0, 0, 0);
    }
    __syncthreads();

    for (int hl = 0; hl < 4; ++hl) {
        const int hh = hgrp * 4 + hl;
        const float acsL = acs4[hl][63];
        const float dec_l = __expf(acsL - acs4[hl][lane]);
        const float dt_l  = dts[hl][lane];
        #pragma unroll
        for (int i = 0; i < 4; ++i) {
            int p0 = w * 16 + i * 4;
            ushort4 xv = *(const ushort4*)&xbc[(size_t)(row0 + lane) * CONVDIM + hh * HEADDIM + p0];
            float x0 = bf2f(xv.x) * dt_l, x1 = bf2f(xv.y) * dt_l;
            float x2 = bf2f(xv.z) * dt_l, x3 = bf2f(xv.w) * dt_l;
            U.p2.Xt [p0+0][lane] = f2bf(x0); U.p2.Xdt[p0+0][lane] = f2bf(x0 * dec_l);
            U.p2.Xt [p0+1][lane] = f2bf(x1); U.p2.Xdt[p0+1][lane] = f2bf(x1 * dec_l);
            U.p2.Xt [p0+2][lane] = f2bf(x2); U.p2.Xdt[p0+2][lane] = f2bf(x2 * dec_l);
            U.p2.Xt [p0+3][lane] = f2bf(x3); U.p2.Xdt[p0+3][lane] = f2bf(x3 * dec_l);
        }
        #pragma unroll
        for (int i = 0; i < 2; ++i)
            #pragma unroll
            for (int j = 0; j < 2; ++j)
                #pragma unroll
                for (int q = 0; q < 4; ++q) {
                    int l = wr*32 + i*16 + (lane >> 4)*4 + q;
                    int s = wc*32 + j*16 + fr;
                    float v = 0.f;
                    if (s < l)       v = accG[i][j][q] * __expf(acs4[hl][l] - acs4[hl][s]);
                    else if (s == l) v = accG[i][j][q] + Dp[hh] / dts[hl][l];
                    U.p2.Ps[l][s] = f2bf(v);
                }
        __syncthreads();
        {
            f32x4 acc[4];
            #pragma unroll
            for (int j = 0; j < 4; ++j) acc[j] = (f32x4)0.f;
            #pragma unroll
            for (int kt = 0; kt < 2; ++kt) {
                bf16x8 af = *(const bf16x8*)&U.p2.Ps[w*16 + fr][kt*32 + kc*8];
                #pragma unroll
                for (int j = 0; j < 4; ++j) {
                    bf16x8 bfv = *(const bf16x8*)&U.p2.Xt[j*16 + fr][kt*32 + kc*8];
                    acc[j] = __builtin_amdgcn_mfma_f32_16x16x32_bf16(af, bfv, acc[j], 0, 0, 0);
                }
            }
            #pragma unroll
            for (int j = 0; j < 4; ++j)
                #pragma unroll
                for (int q = 0; q < 4; ++q) {
                    int l = w*16 + (lane >> 4)*4 + q;
                    int p = j*16 + fr;
                    ybuf[(size_t)(row0 + l) * DINNER + hh * HEADDIM + p] = f2bf(acc[j][q]);
                }
        }
        {
            f32x4 acc2[4][2];
            #pragma unroll
            for (int mt = 0; mt < 4; ++mt)
                #pragma unroll
                for (int jt = 0; jt < 2; ++jt) acc2[mt][jt] = (f32x4)0.f;
            #pragma unroll
            for (int kt = 0; kt < 2; ++kt) {
                bf16x8 a4[4], b2[2];
                #pragma unroll
                for (int mt = 0; mt < 4; ++mt) a4[mt] = *(const bf16x8*)&U.p2.Xdt[mt*16 + fr][kt*32 + kc*8];
                #pragma unroll
                for (int jt = 0; jt < 2; ++jt) b2[jt] = *(const bf16x8*)&Btr[w*32 + jt*16 + fr][kt*32 + kc*8];
                #pragma unroll
                for (int mt = 0; mt < 4; ++mt)
                    #pragma unroll
                    for (int jt = 0; jt < 2; ++jt)
                        acc2[mt][jt] = __builtin_amdgcn_mfma_f32_16x16x32_bf16(a4[mt], b2[jt], acc2[mt][jt], 0, 0, 0);
            }
            ushort* sb = states + ((((size_t)b * NCHUNK + c) * NHEADS + hh) * HEADDIM) * DSTATE;
            #pragma unroll
            for (int mt = 0; mt < 4; ++mt)
                #pragma unroll
                for (int jt = 0; jt < 2; ++jt)
                    #pragma unroll
                    for (int q = 0; q < 4; ++q) {
                        int p = mt*16 + (lane >> 4)*4 + q;
                        int n = w*32 + jt*16 + fr;
                        sb[(size_t)p * DSTATE + n] = f2bf(acc2[mt][jt][q]);
                    }
        }
        __syncthreads();
    }
}

// ------------------------------------- inter-chunk scan (bf16 states, f32 regs)
__global__ __launch_bounds__(256) void scan_k(ushort* __restrict__ states,
                                              const float* __restrict__ chunksum) {
    const int bid = blockIdx.x;
    const int pq = bid & 3, h = (bid >> 2) & 7, b = bid >> 5;
    const int tid = threadIdx.x;
    float pref[8];
    #pragma unroll
    for (int k = 0; k < 8; ++k) pref[k] = 0.f;
    for (int c = 0; c < NCHUNK; ++c) {
        ushort* base = states + (((size_t)b * NCHUNK + c) * NHEADS + h) * (HEADDIM * DSTATE)
                       + pq * 2048 + tid * 8;
        float dec = __expf(chunksum[((size_t)b * NCHUNK + c) * NHEADS + h]);
        uint4 v = *(const uint4*)base;
        const ushort* pv = (const ushort*)&v;
        ushort outv[8];
        #pragma unroll
        for (int j = 0; j < 8; ++j) {
            float cur = bf2f(pv[j]);
            outv[j] = f2bf(pref[j]);
            pref[j] = dec * pref[j] + cur;
        }
        *(uint4*)base = *(uint4*)outv;
    }
}

// ------------------- Y_off += C @ S^T * ea, then gate+RMSNorm, write bf16 g
#define YLDS 520
__global__ __launch_bounds__(256) void yoff_gate_k(const ushort* __restrict__ xbc,
                                                   const ushort* __restrict__ states,
                                                   const float* __restrict__ acsbuf,
                                                   const ushort* __restrict__ ybuf,
                                                   const ushort* __restrict__ zx,
                                                   const float* __restrict__ nw,
                                                   ushort* __restrict__ gbuf) {
    const int c = blockIdx.x, b = blockIdx.y;
    const int row0 = b * SEQ + c * LCHUNK;
    const int tid = threadIdx.x;
    const int lane = tid & 63, w = tid >> 6;
    const int fr = lane & 15, kc = lane >> 4;
    __shared__ ushort Csh[64][SLDA];
    __shared__ ushort Ssh[64][SLDA];
    __shared__ ushort Ys[64][YLDS];
    __shared__ float eah[64];

    for (int it = 0; it < 4; ++it) {
        int idx = tid + it * 256;
        int l = idx >> 4, ng = idx & 15;
        *(uint4*)&Csh[l][ng * 8] =
            *(const uint4*)&xbc[(size_t)(row0 + l) * CONVDIM + DINNER + DSTATE + ng * 8];
    }
    for (int hl = 0; hl < NHEADS; ++hl) {
        __syncthreads();
        const ushort* sb = states + ((((size_t)b * NCHUNK + c) * NHEADS + hl) * HEADDIM) * DSTATE;
        for (int it = 0; it < 4; ++it) {
            int idx = tid + it * 256;
            int p = idx >> 4, ng = idx & 15;
            *(uint4*)&Ssh[p][ng * 8] = *(const uint4*)&sb[(size_t)p * DSTATE + ng * 8];
        }
        if (tid < 64)
            eah[tid] = __expf(acsbuf[(((size_t)b * NCHUNK + c) * NHEADS + hl) * LCHUNK + tid]);
        __syncthreads();
        f32x4 acc[4];
        #pragma unroll
        for (int j = 0; j < 4; ++j) acc[j] = (f32x4)0.f;
        #pragma unroll
        for (int kt = 0; kt < 4; ++kt) {
            bf16x8 af = *(const bf16x8*)&Csh[w*16 + fr][kt*32 + kc*8];
            #pragma unroll
            for (int j = 0; j < 4; ++j) {
                bf16x8 bfv = *(const bf16x8*)&Ssh[j*16 + fr][kt*32 + kc*8];
                acc[j] = __builtin_amdgcn_mfma_f32_16x16x32_bf16(af, bfv, acc[j], 0, 0, 0);
            }
        }
        #pragma unroll
        for (int j = 0; j < 4; ++j)
            #pragma unroll
            for (int q = 0; q < 4; ++q) {
                int l = w*16 + (lane >> 4)*4 + q;
                int p = j*16 + fr;
                float val = bf2f(ybuf[(size_t)(row0 + l) * DINNER + hl * HEADDIM + p])
                            + acc[j][q] * eah[l];
                Ys[l][hl * HEADDIM + p] = f2bf(val);
            }
    }
    __syncthreads();
    float nwv[8];
    #pragma unroll
    for (int j = 0; j < 8; ++j) nwv[j] = nw[lane * 8 + j];
    for (int i = 0; i < 16; ++i) {
        int l = w * 16 + i;
        int row = row0 + l;
        uint4 zv = *(const uint4*)&zx[(size_t)row * ZXLD + lane * 8];
        const ushort* pz = (const ushort*)&zv;
        float g[8], ss = 0.f;
        #pragma unroll
        for (int j = 0; j < 8; ++j) {
            float y = bf2f(Ys[l][lane * 8 + j]);
            float z = bf2f(pz[j]);
            float sz = z / (1.f + __expf(-z));
            g[j] = y * sz;
            ss += g[j] * g[j];
        }
        #pragma unroll
        for (int off = 32; off; off >>= 1) ss += __shfl_xor(ss, off);
        float r = rsqrtf(ss / (float)DINNER + EPSV);
        ushort res[8];
        #pragma unroll
        for (int j = 0; j < 8; ++j) res[j] = f2bf(g[j] * r * nwv[j]);
        *(uint4*)&gbuf[(size_t)row * DINNER + lane * 8] = *(uint4*)res;
    }
}

// ---------------------------------------------------------------- launch
extern "C" void kernel_launch(void* const* d_in, const int* in_sizes, int n_in,
                              void* d_out, int out_size, void* d_ws, size_t ws_size,
                              hipStream_t stream) {
    const float* u       = (const float*)d_in[0];
    const float* W_in    = (const float*)d_in[1];
    const float* conv_w  = (const float*)d_in[2];
    const float* conv_b  = (const float*)d_in[3];
    const float* dt_bias = (const float*)d_in[4];
    const float* A_log   = (const float*)d_in[5];
    const float* Dp      = (const float*)d_in[6];
    const float* norm_w  = (const float*)d_in[7];
    const float* W_out   = (const float*)d_in[8];
    float* out = (float*)d_out;

    char* p = (char*)d_ws;
    ushort* zx       = (ushort*)p; p += (size_t)ROWS * ZXLD * sizeof(ushort);
    ushort* ybuf     = (ushort*)p; p += (size_t)ROWS * DINNER * sizeof(ushort);
    ushort* gbuf     = (ushort*)p; p += (size_t)ROWS * DINNER * sizeof(ushort);
    ushort* states   = (ushort*)p; p += (size_t)BATCHN * NCHUNK * NHEADS * HEADDIM * DSTATE * sizeof(ushort);
    ushort* xbc      = (ushort*)p; p += (size_t)ROWS * CONVDIM * sizeof(ushort);
    ushort* ubf      = (ushort*)p; p += (size_t)ROWS * DMODEL * sizeof(ushort);
    float*  dtb      = (float*)p;  p += (size_t)ROWS * NHEADS  * sizeof(float);
    float*  adtb     = (float*)p;  p += (size_t)ROWS * NHEADS  * sizeof(float);
    float*  chunksum = (float*)p;  p += (size_t)BATCHN * NCHUNK * NHEADS * sizeof(float);
    float*  acsbuf   = (float*)p;  p += (size_t)BATCHN * NCHUNK * NHEADS * LCHUNK * sizeof(float);
    ushort* WtA      = (ushort*)p; p += (size_t)ZXLD * DMODEL * sizeof(ushort);
    ushort* WtB      = (ushort*)p; p += (size_t)DMODEL * DINNER * sizeof(ushort);

    transpose_cast_k<<<dim3(ZXLD/32, DMODEL/32), 256, 0, stream>>>(W_in,  WtA, DMODEL, DINPROJ, 0);
    transpose_cast_k<<<dim3(DMODEL/32, DINNER/32), 256, 0, stream>>>(W_out, WtB, DINNER, DMODEL, 0);
    cast_bf16_k<<<ROWS*DMODEL/8/256, 256, 0, stream>>>(u, ubf);
    // in-proj -> bf16 zx   (1-D swizzled grid: 10 n-tiles x 128 m-tiles)
    gemm_bf16<ushort><<<(ZXLD/128)*(ROWS/128), 256, 0, stream>>>(
        ubf, WtA, zx, ROWS, ZXLD, DMODEL, ZXLD/128);
    dt_fused_k<<<ROWS/32, 256, 0, stream>>>(u, W_in, dt_bias, A_log, dtb, adtb);
    conv_silu_k<<<(ROWS/4)*96/256, 256, 0, stream>>>(zx, conv_w, conv_b, xbc);
    ssd_mfma_k<<<dim3(NCHUNK, BATCHN, 2), 256, 0, stream>>>(
        xbc, dtb, adtb, Dp, ybuf, states, acsbuf, chunksum);
    scan_k<<<BATCHN*NHEADS*4, 256, 0, stream>>>(states, chunksum);
    yoff_gate_k<<<dim3(NCHUNK, BATCHN), 256, 0, stream>>>(
        xbc, states, acsbuf, ybuf, zx, norm_w, gbuf);
    // out-proj from bf16 g  (2 n-tiles x 128 m-tiles)
    gemm_bf16<float><<<(DMODEL/128)*(ROWS/128), 256, 0, stream>>>(
        gbuf, WtB, out, ROWS, DMODEL, DINNER, DMODEL/128);
}

// Round 8
// 131.445 us; speedup vs baseline: 1.7237x; 1.0619x over previous
//
#include <hip/hip_runtime.h>
#include <hip/hip_bf16.h>
#include <math.h>

#define BATCHN  16
#define SEQ     1024
#define DMODEL  256
#define DSTATE  128
#define HEADDIM 64
#define DINNER  512
#define NHEADS  8
#define CONVDIM 768
#define DINPROJ 1288
#define ZXLD    1280
#define KCONV   4
#define NCHUNK  16
#define LCHUNK  64
#define EPSV    1e-5f
#define ROWS    (BATCHN*SEQ)

typedef __attribute__((ext_vector_type(8))) __bf16 bf16x8;
typedef __attribute__((ext_vector_type(4))) float  f32x4;

__device__ inline ushort f2bf(float f) {
    union { float f; uint32_t u; } v; v.f = f;
    uint32_t r = v.u + 0x7fff + ((v.u >> 16) & 1);
    return (ushort)(r >> 16);
}
__device__ inline float bf2f(ushort u) {
    union { uint32_t u; float f; } v; v.u = ((uint32_t)u) << 16;
    return v.f;
}

// ------------------- merged W_in/W_out transpose + cast to bf16 (448 blocks)
__global__ __launch_bounds__(256) void transpose_cast2_k(const float* __restrict__ W_in,
                                                         const float* __restrict__ W_out,
                                                         ushort* __restrict__ WtA,
                                                         ushort* __restrict__ WtB) {
    __shared__ float Ts[32][33];
    int bid = blockIdx.x;
    const float* src; ushort* dst; int K, ldsrc, nx;
    if (bid < 320) { src = W_in;  dst = WtA; K = DMODEL; ldsrc = DINPROJ; nx = 40; }
    else { bid -= 320; src = W_out; dst = WtB; K = DINNER; ldsrc = DMODEL; nx = 8; }
    const int n0 = (bid % nx) * 32, k0 = (bid / nx) * 32;
    const int tx = threadIdx.x & 31, ty = threadIdx.x >> 5;
    #pragma unroll
    for (int j = 0; j < 4; ++j) {
        int kl = ty * 4 + j;
        Ts[kl][tx] = src[(size_t)(k0 + kl) * ldsrc + n0 + tx];
    }
    __syncthreads();
    #pragma unroll
    for (int j = 0; j < 4; ++j) {
        int nl = ty * 4 + j;
        dst[(size_t)(n0 + nl) * K + k0 + tx] = f2bf(Ts[tx][nl]);
    }
}

// -------------- dt GEMV (exact f32) + u -> bf16 cast, one u read total
__global__ __launch_bounds__(256) void dt_cast_k(const float* __restrict__ u,
                                                 const float* __restrict__ W_in,
                                                 const float* __restrict__ dt_bias,
                                                 const float* __restrict__ A_log,
                                                 ushort* __restrict__ ubf,
                                                 float* __restrict__ dtb,
                                                 float* __restrict__ adtb) {
    __shared__ float Uld[32][264];           // 32 rows of u, padded
    __shared__ float Ws[DMODEL][NHEADS];
    const int tid = threadIdx.x;
    #pragma unroll
    for (int j = 0; j < 8; ++j) {
        int idx = tid + j * 256;
        Ws[idx >> 3][idx & 7] = W_in[(size_t)(idx >> 3) * DINPROJ + 1280 + (idx & 7)];
    }
    const int row0 = blockIdx.x * 32;
    // coalesced staging: 8 iters x (256 thr x float4) = 8192 elems = 32 rows
    #pragma unroll
    for (int v = 0; v < 8; ++v) {
        int e = v * 1024 + tid * 4;          // flat elem in 32x256 block
        int r = e >> 8, cc = e & 255;
        float4 x = *(const float4*)&u[(size_t)(row0 + r) * DMODEL + cc];
        *(float4*)&Uld[r][cc] = x;
        ushort t4[4];
        t4[0]=f2bf(x.x); t4[1]=f2bf(x.y); t4[2]=f2bf(x.z); t4[3]=f2bf(x.w);
        *(ushort4*)&ubf[(size_t)(row0 + r) * DMODEL + cc] = *(ushort4*)t4;
    }
    __syncthreads();
    const int row = tid >> 3, h = tid & 7;
    float acc = 0.f;
    #pragma unroll 8
    for (int k = 0; k < DMODEL; k += 4) {
        float4 uv = *(const float4*)&Uld[row][k];
        acc += uv.x * Ws[k][h] + uv.y * Ws[k+1][h] + uv.z * Ws[k+2][h] + uv.w * Ws[k+3][h];
    }
    float v = acc + dt_bias[h];
    float dt = (v > 20.f) ? v : log1pf(__expf(v));
    dtb [(size_t)(row0 + row) * NHEADS + h] = dt;
    adtb[(size_t)(row0 + row) * NHEADS + h] = dt * (-__expf(A_log[h]));
}

// ------------------------------------------------------- bf16 MFMA GEMM
#define LDSW 72
template<typename CT>
__global__ __launch_bounds__(256) void gemm_bf16(const ushort* __restrict__ A,
                                                 const ushort* __restrict__ Bt,
                                                 CT* __restrict__ C,
                                                 int M, int N, int K, int nx) {
    __shared__ ushort As[128 * LDSW];
    __shared__ ushort Bs[128 * LDSW];
    const int tid  = threadIdx.x;
    const int nwg  = gridDim.x;
    const int work = (blockIdx.x & 7) * (nwg >> 3) + (blockIdx.x >> 3);
    const int m0 = (work / nx) * 128, n0 = (work % nx) * 128;
    const int wid = tid >> 6, lane = tid & 63;
    const int wr = wid >> 1, wc = wid & 1;
    const int r = tid >> 1, kq = tid & 1;
    const int fr = lane & 15, kc = lane >> 4;

    f32x4 acc[4][4];
    #pragma unroll
    for (int i = 0; i < 4; ++i)
        #pragma unroll
        for (int j = 0; j < 4; ++j) acc[i][j] = (f32x4)0.f;

    for (int kt = 0; kt < K; kt += 64) {
        const ushort* ap = &A [(size_t)(m0 + r) * K + kt + kq * 32];
        const ushort* bp = &Bt[(size_t)(n0 + r) * K + kt + kq * 32];
        #pragma unroll
        for (int v = 0; v < 4; ++v) {
            *(uint4*)&As[r * LDSW + kq * 32 + v * 8] = *(const uint4*)(ap + v * 8);
            *(uint4*)&Bs[r * LDSW + kq * 32 + v * 8] = *(const uint4*)(bp + v * 8);
        }
        __syncthreads();
        #pragma unroll
        for (int kk = 0; kk < 2; ++kk) {
            bf16x8 af[4], bfv[4];
            #pragma unroll
            for (int i = 0; i < 4; ++i) {
                af[i]  = *(const bf16x8*)&As[(wr * 64 + i * 16 + fr) * LDSW + kk * 32 + kc * 8];
                bfv[i] = *(const bf16x8*)&Bs[(wc * 64 + i * 16 + fr) * LDSW + kk * 32 + kc * 8];
            }
            #pragma unroll
            for (int i = 0; i < 4; ++i)
                #pragma unroll
                for (int j = 0; j < 4; ++j)
                    acc[i][j] = __builtin_amdgcn_mfma_f32_16x16x32_bf16(af[i], bfv[j], acc[i][j], 0, 0, 0);
        }
        __syncthreads();
    }
    #pragma unroll
    for (int i = 0; i < 4; ++i)
        #pragma unroll
        for (int j = 0; j < 4; ++j)
            #pragma unroll
            for (int q = 0; q < 4; ++q) {
                int rr = m0 + wr * 64 + i * 16 + (lane >> 4) * 4 + q;
                int cc = n0 + wc * 64 + j * 16 + (lane & 15);
                if constexpr (sizeof(CT) == 4) C[(size_t)rr * N + cc] = acc[i][j][q];
                else                           C[(size_t)rr * N + cc] = f2bf(acc[i][j][q]);
            }
}

// ------------------- depthwise conv + SiLU: LDS weights, 4 t-steps/thread
__global__ __launch_bounds__(256) void conv_silu_k(const ushort* __restrict__ zx,
                                                   const float* __restrict__ cw,
                                                   const float* __restrict__ cb,
                                                   ushort* __restrict__ out) {
    __shared__ float cws[KCONV][CONVDIM];
    __shared__ float cbs[CONVDIM];
    const int tid = threadIdx.x;
    #pragma unroll
    for (int it = 0; it < 3; ++it) {
        int i = tid + it * 256;
        cbs[i] = cb[i];
        #pragma unroll
        for (int k = 0; k < KCONV; ++k) cws[k][i] = cw[i * KCONV + k];
    }
    __syncthreads();

    const int idx = blockIdx.x * 256 + tid;
    const int cg = idx % 96, btq = idx / 96;
    const int c0 = cg * 8;
    const int bt0 = btq * 4;
    const int t0 = bt0 & (SEQ - 1);

    float wv[KCONV][8], bias[8];
    #pragma unroll
    for (int j = 0; j < 8; ++j) bias[j] = cbs[c0 + j];
    #pragma unroll
    for (int k = 0; k < KCONV; ++k) {
        float4 a = *(const float4*)&cws[k][c0];
        float4 b = *(const float4*)&cws[k][c0 + 4];
        wv[k][0] = a.x; wv[k][1] = a.y; wv[k][2] = a.z; wv[k][3] = a.w;
        wv[k][4] = b.x; wv[k][5] = b.y; wv[k][6] = b.z; wv[k][7] = b.w;
    }
    float xr[7][8];
    #pragma unroll
    for (int r = 0; r < 7; ++r) {
        int tt = t0 - 3 + r;
        if (tt >= 0) {
            uint4 v = *(const uint4*)&zx[(size_t)(bt0 - 3 + r) * ZXLD + DINNER + c0];
            const ushort* pv = (const ushort*)&v;
            #pragma unroll
            for (int j = 0; j < 8; ++j) xr[r][j] = bf2f(pv[j]);
        } else {
            #pragma unroll
            for (int j = 0; j < 8; ++j) xr[r][j] = 0.f;
        }
    }
    #pragma unroll
    for (int dt = 0; dt < 4; ++dt) {
        float acc[8];
        #pragma unroll
        for (int j = 0; j < 8; ++j) acc[j] = bias[j];
        #pragma unroll
        for (int k = 0; k < KCONV; ++k)
            #pragma unroll
            for (int j = 0; j < 8; ++j) acc[j] += xr[dt + k][j] * wv[k][j];
        ushort res[8];
        #pragma unroll
        for (int j = 0; j < 8; ++j)
            res[j] = f2bf(acc[j] / (1.f + __expf(-acc[j])));
        *(uint4*)&out[(size_t)(bt0 + dt) * CONVDIM + c0] = *(uint4*)res;
    }
}

// -------------------------------------------------- SSD MFMA kernel
#define SLDA 136
#define SLDB 72
__global__ __launch_bounds__(256) void ssd_mfma_k(const ushort* __restrict__ xbc,
                                                  const float* __restrict__ dtb,
                                                  const float* __restrict__ adtb,
                                                  const float* __restrict__ Dp,
                                                  ushort* __restrict__ ybuf,
                                                  ushort* __restrict__ states,
                                                  float* __restrict__ acsbuf,
                                                  float* __restrict__ chunksum) {
    const int c = blockIdx.x, b = blockIdx.y, hgrp = blockIdx.z;
    const int row0 = b * SEQ + c * LCHUNK;
    const int tid = threadIdx.x;
    const int lane = tid & 63, w = tid >> 6;
    const int fr = lane & 15, kc = lane >> 4;

    __shared__ union {
        struct { ushort Bs[64][SLDA]; ushort Cs[64][SLDA]; } p1;
        struct { ushort Ps[64][SLDB]; ushort Xt[64][SLDB]; ushort Xdt[64][SLDB]; } p2;
    } U;
    __shared__ ushort Btr[128][SLDB];
    __shared__ float acs4[4][64];
    __shared__ float dts[4][64];
    __shared__ float decs[4][64];   // exp(acs[63]-acs[l]) per head

    {
        const int hh = hgrp * 4 + w;
        float v = adtb[(size_t)(row0 + lane) * NHEADS + hh];
        #pragma unroll
        for (int off = 1; off < 64; off <<= 1) {
            float t = __shfl_up(v, off);
            if (lane >= off) v += t;
        }
        acs4[w][lane] = v;
        float tot = __shfl(v, 63);
        decs[w][lane] = __expf(tot - v);
        acsbuf[(((size_t)b * NCHUNK + c) * NHEADS + hh) * LCHUNK + lane] = v;
        if (lane == 63) chunksum[((size_t)b * NCHUNK + c) * NHEADS + hh] = v;
        dts[w][lane] = dtb[(size_t)(row0 + lane) * NHEADS + hh];
    }
    for (int it = 0; it < 4; ++it) {
        int idx = tid + it * 256;
        int l = idx >> 4, ng = idx & 15;
        const ushort* rp = &xbc[(size_t)(row0 + l) * CONVDIM + DINNER];
        uint4 vb = *(const uint4*)(rp + ng * 8);
        *(uint4*)&U.p1.Bs[l][ng * 8] = vb;
        uint4 vc = *(const uint4*)(rp + DSTATE + ng * 8);
        *(uint4*)&U.p1.Cs[l][ng * 8] = vc;
        const ushort* pv = (const ushort*)&vb;
        #pragma unroll
        for (int j = 0; j < 8; ++j) Btr[ng * 8 + j][l] = pv[j];
    }
    __syncthreads();

    const int wr = w >> 1, wc = w & 1;
    f32x4 accG[2][2];
    #pragma unroll
    for (int i = 0; i < 2; ++i)
        #pragma unroll
        for (int j = 0; j < 2; ++j) accG[i][j] = (f32x4)0.f;
    #pragma unroll
    for (int kt = 0; kt < 4; ++kt) {
        bf16x8 af[2], bfv[2];
        #pragma unroll
        for (int i = 0; i < 2; ++i) af[i]  = *(const bf16x8*)&U.p1.Cs[wr*32 + i*16 + fr][kt*32 + kc*8];
        #pragma unroll
        for (int j = 0; j < 2; ++j) bfv[j] = *(const bf16x8*)&U.p1.Bs[wc*32 + j*16 + fr][kt*32 + kc*8];
        #pragma unroll
        for (int i = 0; i < 2; ++i)
            #pragma unroll
            for (int j = 0; j < 2; ++j)
                accG[i][j] = __builtin_amdgcn_mfma_f32_16x16x32_bf16(af[i], bfv[j], accG[i][j], 0, 0, 0);
    }
    __syncthreads();

    for (int hl = 0; hl < 4; ++hl) {
        const int hh = hgrp * 4 + hl;
        {
            const int p = lane;
            ushort xt[16], xdt[16];
            #pragma unroll
            for (int j = 0; j < 16; ++j) {
                int l = w * 16 + j;
                float xv = bf2f(xbc[(size_t)(row0 + l) * CONVDIM + hh * HEADDIM + p])
                           * dts[hl][l];
                xt[j]  = f2bf(xv);
                xdt[j] = f2bf(xv * decs[hl][l]);
            }
            #pragma unroll
            for (int v = 0; v < 4; ++v) {
                *(ushort4*)&U.p2.Xt [p][w*16 + v*4] = *(ushort4*)&xt[v*4];
                *(ushort4*)&U.p2.Xdt[p][w*16 + v*4] = *(ushort4*)&xdt[v*4];
            }
        }
        #pragma unroll
        for (int i = 0; i < 2; ++i)
            #pragma unroll
            for (int j = 0; j < 2; ++j)
                #pragma unroll
                for (int q = 0; q < 4; ++q) {
                    int l = wr*32 + i*16 + (lane >> 4)*4 + q;
                    int s = wc*32 + j*16 + fr;
                    float v = 0.f;
                    if (s < l)       v = accG[i][j][q] * __expf(acs4[hl][l] - acs4[hl][s]);
                    else if (s == l) v = accG[i][j][q] + Dp[hh] / dts[hl][l];
                    U.p2.Ps[l][s] = f2bf(v);
                }
        __syncthreads();
        {
            f32x4 acc[4];
            #pragma unroll
            for (int j = 0; j < 4; ++j) acc[j] = (f32x4)0.f;
            #pragma unroll
            for (int kt = 0; kt < 2; ++kt) {
                bf16x8 af = *(const bf16x8*)&U.p2.Ps[w*16 + fr][kt*32 + kc*8];
                #pragma unroll
                for (int j = 0; j < 4; ++j) {
                    bf16x8 bfv = *(const bf16x8*)&U.p2.Xt[j*16 + fr][kt*32 + kc*8];
                    acc[j] = __builtin_amdgcn_mfma_f32_16x16x32_bf16(af, bfv, acc[j], 0, 0, 0);
                }
            }
            #pragma unroll
            for (int j = 0; j < 4; ++j)
                #pragma unroll
                for (int q = 0; q < 4; ++q) {
                    int l = w*16 + (lane >> 4)*4 + q;
                    int p = j*16 + fr;
                    ybuf[(size_t)(row0 + l) * DINNER + hh * HEADDIM + p] = f2bf(acc[j][q]);
                }
        }
        {
            f32x4 acc2[4][2];
            #pragma unroll
            for (int mt = 0; mt < 4; ++mt)
                #pragma unroll
                for (int jt = 0; jt < 2; ++jt) acc2[mt][jt] = (f32x4)0.f;
            #pragma unroll
            for (int kt = 0; kt < 2; ++kt) {
                bf16x8 a4[4], b2[2];
                #pragma unroll
                for (int mt = 0; mt < 4; ++mt) a4[mt] = *(const bf16x8*)&U.p2.Xdt[mt*16 + fr][kt*32 + kc*8];
                #pragma unroll
                for (int jt = 0; jt < 2; ++jt) b2[jt] = *(const bf16x8*)&Btr[w*32 + jt*16 + fr][kt*32 + kc*8];
                #pragma unroll
                for (int mt = 0; mt < 4; ++mt)
                    #pragma unroll
                    for (int jt = 0; jt < 2; ++jt)
                        acc2[mt][jt] = __builtin_amdgcn_mfma_f32_16x16x32_bf16(a4[mt], b2[jt], acc2[mt][jt], 0, 0, 0);
            }
            ushort* sb = states + ((((size_t)b * NCHUNK + c) * NHEADS + hh) * HEADDIM) * DSTATE;
            #pragma unroll
            for (int mt = 0; mt < 4; ++mt)
                #pragma unroll
                for (int jt = 0; jt < 2; ++jt)
                    #pragma unroll
                    for (int q = 0; q < 4; ++q) {
                        int p = mt*16 + (lane >> 4)*4 + q;
                        int n = w*32 + jt*16 + fr;
                        sb[(size_t)p * DSTATE + n] = f2bf(acc2[mt][jt][q]);
                    }
        }
        __syncthreads();
    }
}

// ------------------------------------- inter-chunk scan (bf16 states, f32 regs)
__global__ __launch_bounds__(256) void scan_k(ushort* __restrict__ states,
                                              const float* __restrict__ chunksum) {
    const int bid = blockIdx.x;
    const int pq = bid & 3, h = (bid >> 2) & 7, b = bid >> 5;
    const int tid = threadIdx.x;
    float pref[8];
    #pragma unroll
    for (int k = 0; k < 8; ++k) pref[k] = 0.f;
    for (int c = 0; c < NCHUNK; ++c) {
        ushort* base = states + (((size_t)b * NCHUNK + c) * NHEADS + h) * (HEADDIM * DSTATE)
                       + pq * 2048 + tid * 8;
        float dec = __expf(chunksum[((size_t)b * NCHUNK + c) * NHEADS + h]);
        uint4 v = *(const uint4*)base;
        const ushort* pv = (const ushort*)&v;
        ushort outv[8];
        #pragma unroll
        for (int j = 0; j < 8; ++j) {
            float cur = bf2f(pv[j]);
            outv[j] = f2bf(pref[j]);
            pref[j] = dec * pref[j] + cur;
        }
        *(uint4*)base = *(uint4*)outv;
    }
}

// ------------------- Y_off += C @ S^T * ea, then gate+RMSNorm, write bf16 g
#define YLDS 520
__global__ __launch_bounds__(256) void yoff_gate_k(const ushort* __restrict__ xbc,
                                                   const ushort* __restrict__ states,
                                                   const float* __restrict__ acsbuf,
                                                   const ushort* __restrict__ ybuf,
                                                   const ushort* __restrict__ zx,
                                                   const float* __restrict__ nw,
                                                   ushort* __restrict__ gbuf) {
    const int c = blockIdx.x, b = blockIdx.y;
    const int row0 = b * SEQ + c * LCHUNK;
    const int tid = threadIdx.x;
    const int lane = tid & 63, w = tid >> 6;
    const int fr = lane & 15, kc = lane >> 4;
    __shared__ ushort Csh[64][SLDA];
    __shared__ ushort Ssh[64][SLDA];
    __shared__ ushort Ys[64][YLDS];
    __shared__ float eah[64];

    for (int it = 0; it < 4; ++it) {
        int idx = tid + it * 256;
        int l = idx >> 4, ng = idx & 15;
        *(uint4*)&Csh[l][ng * 8] =
            *(const uint4*)&xbc[(size_t)(row0 + l) * CONVDIM + DINNER + DSTATE + ng * 8];
    }
    for (int hl = 0; hl < NHEADS; ++hl) {
        __syncthreads();
        const ushort* sb = states + ((((size_t)b * NCHUNK + c) * NHEADS + hl) * HEADDIM) * DSTATE;
        for (int it = 0; it < 4; ++it) {
            int idx = tid + it * 256;
            int p = idx >> 4, ng = idx & 15;
            *(uint4*)&Ssh[p][ng * 8] = *(const uint4*)&sb[(size_t)p * DSTATE + ng * 8];
        }
        if (tid < 64)
            eah[tid] = __expf(acsbuf[(((size_t)b * NCHUNK + c) * NHEADS + hl) * LCHUNK + tid]);
        __syncthreads();
        f32x4 acc[4];
        #pragma unroll
        for (int j = 0; j < 4; ++j) acc[j] = (f32x4)0.f;
        #pragma unroll
        for (int kt = 0; kt < 4; ++kt) {
            bf16x8 af = *(const bf16x8*)&Csh[w*16 + fr][kt*32 + kc*8];
            #pragma unroll
            for (int j = 0; j < 4; ++j) {
                bf16x8 bfv = *(const bf16x8*)&Ssh[j*16 + fr][kt*32 + kc*8];
                acc[j] = __builtin_amdgcn_mfma_f32_16x16x32_bf16(af, bfv, acc[j], 0, 0, 0);
            }
        }
        #pragma unroll
        for (int j = 0; j < 4; ++j)
            #pragma unroll
            for (int q = 0; q < 4; ++q) {
                int l = w*16 + (lane >> 4)*4 + q;
                int p = j*16 + fr;
                float val = bf2f(ybuf[(size_t)(row0 + l) * DINNER + hl * HEADDIM + p])
                            + acc[j][q] * eah[l];
                Ys[l][hl * HEADDIM + p] = f2bf(val);
            }
    }
    __syncthreads();
    float nwv[8];
    #pragma unroll
    for (int j = 0; j < 8; ++j) nwv[j] = nw[lane * 8 + j];
    for (int i = 0; i < 16; ++i) {
        int l = w * 16 + i;
        int row = row0 + l;
        uint4 zv = *(const uint4*)&zx[(size_t)row * ZXLD + lane * 8];
        const ushort* pz = (const ushort*)&zv;
        float g[8], ss = 0.f;
        #pragma unroll
        for (int j = 0; j < 8; ++j) {
            float y = bf2f(Ys[l][lane * 8 + j]);
            float z = bf2f(pz[j]);
            float sz = z / (1.f + __expf(-z));
            g[j] = y * sz;
            ss += g[j] * g[j];
        }
        #pragma unroll
        for (int off = 32; off; off >>= 1) ss += __shfl_xor(ss, off);
        float r = rsqrtf(ss / (float)DINNER + EPSV);
        ushort res[8];
        #pragma unroll
        for (int j = 0; j < 8; ++j) res[j] = f2bf(g[j] * r * nwv[j]);
        *(uint4*)&gbuf[(size_t)row * DINNER + lane * 8] = *(uint4*)res;
    }
}

// ---------------------------------------------------------------- launch
extern "C" void kernel_launch(void* const* d_in, const int* in_sizes, int n_in,
                              void* d_out, int out_size, void* d_ws, size_t ws_size,
                              hipStream_t stream) {
    const float* u       = (const float*)d_in[0];
    const float* W_in    = (const float*)d_in[1];
    const float* conv_w  = (const float*)d_in[2];
    const float* conv_b  = (const float*)d_in[3];
    const float* dt_bias = (const float*)d_in[4];
    const float* A_log   = (const float*)d_in[5];
    const float* Dp      = (const float*)d_in[6];
    const float* norm_w  = (const float*)d_in[7];
    const float* W_out   = (const float*)d_in[8];
    float* out = (float*)d_out;

    char* p = (char*)d_ws;
    ushort* zx       = (ushort*)p; p += (size_t)ROWS * ZXLD * sizeof(ushort);
    ushort* ybuf     = (ushort*)p; p += (size_t)ROWS * DINNER * sizeof(ushort);
    ushort* gbuf     = (ushort*)p; p += (size_t)ROWS * DINNER * sizeof(ushort);
    ushort* states   = (ushort*)p; p += (size_t)BATCHN * NCHUNK * NHEADS * HEADDIM * DSTATE * sizeof(ushort);
    ushort* xbc      = (ushort*)p; p += (size_t)ROWS * CONVDIM * sizeof(ushort);
    ushort* ubf      = (ushort*)p; p += (size_t)ROWS * DMODEL * sizeof(ushort);
    float*  dtb      = (float*)p;  p += (size_t)ROWS * NHEADS  * sizeof(float);
    float*  adtb     = (float*)p;  p += (size_t)ROWS * NHEADS  * sizeof(float);
    float*  chunksum = (float*)p;  p += (size_t)BATCHN * NCHUNK * NHEADS * sizeof(float);
    float*  acsbuf   = (float*)p;  p += (size_t)BATCHN * NCHUNK * NHEADS * LCHUNK * sizeof(float);
    ushort* WtA      = (ushort*)p; p += (size_t)ZXLD * DMODEL * sizeof(ushort);
    ushort* WtB      = (ushort*)p; p += (size_t)DMODEL * DINNER * sizeof(ushort);

    dt_cast_k<<<ROWS/32, 256, 0, stream>>>(u, W_in, dt_bias, A_log, ubf, dtb, adtb);
    transpose_cast2_k<<<448, 256, 0, stream>>>(W_in, W_out, WtA, WtB);
    gemm_bf16<ushort><<<(ZXLD/128)*(ROWS/128), 256, 0, stream>>>(
        ubf, WtA, zx, ROWS, ZXLD, DMODEL, ZXLD/128);
    conv_silu_k<<<(ROWS/4)*96/256, 256, 0, stream>>>(zx, conv_w, conv_b, xbc);
    ssd_mfma_k<<<dim3(NCHUNK, BATCHN, 2), 256, 0, stream>>>(
        xbc, dtb, adtb, Dp, ybuf, states, acsbuf, chunksum);
    scan_k<<<BATCHN*NHEADS*4, 256, 0, stream>>>(states, chunksum);
    yoff_gate_k<<<dim3(NCHUNK, BATCHN), 256, 0, stream>>>(
        xbc, states, acsbuf, ybuf, zx, norm_w, gbuf);
    gemm_bf16<float><<<(DMODEL/128)*(ROWS/128), 256, 0, stream>>>(
        gbuf, WtB, out, ROWS, DMODEL, DINNER, DMODEL/128);
}